// Round 21
// baseline (938.889 us; speedup 1.0000x reference)
//
#include <hip/hip_runtime.h>
#include <math.h>

typedef __attribute__((ext_vector_type(8))) short bf16x8;
typedef __attribute__((ext_vector_type(4))) float f32x4;

namespace {
constexpr int Bc = 2, Tc = 1024, Dc = 1024, Hc = 16, Fc = 2730;
constexpr int Fp = 2752;   // padded F (K of wout GEMM)
constexpr int Gp = 5504;   // padded 2F (N of gate GEMM)
constexpr int Mc = Bc * Tc;               // 2048 rows
constexpr float EPSc = 1e-6f;
constexpr float NEGc = -10000.0f;
constexpr float SCALEc = 0.125f;          // 1/sqrt(64)
}

// fp32 -> bf16 RTNE (finite values only, which holds here)
__device__ __forceinline__ unsigned short f2b(float f) {
    unsigned int u = __float_as_uint(f);
    u += 0x7FFFu + ((u >> 16) & 1u);
    return (unsigned short)(u >> 16);
}

// ---------------- embedding gather (fp32 x) ----------------
__global__ void k_embed(const int* __restrict__ ids, const float* __restrict__ ew,
                        float* __restrict__ x) {
    int row = blockIdx.x;
    int id = ids[row];
    const float4* src = (const float4*)(ew + (size_t)id * Dc);
    float4* dst = (float4*)(x + (size_t)row * Dc);
    dst[threadIdx.x] = src[threadIdx.x];
}

// ---------------- straight fp32 -> bf16 convert, rows of 1024 (embedding) ----------------
__global__ void k_conv(const float* __restrict__ in, unsigned short* __restrict__ out) {
    size_t i = ((size_t)blockIdx.x * 256 + threadIdx.x) * 4;
    float4 v = *(const float4*)(in + i);
    ushort4 o;
    o.x = f2b(v.x); o.y = f2b(v.y); o.z = f2b(v.z); o.w = f2b(v.w);
    *(ushort4*)(out + i) = o;
}

// ---------------- fused per-layer weight convert (wq | wo | wg-interleave | ww-padk) ----------------
__global__ void k_conv_layer(const float* __restrict__ wq, const float* __restrict__ wo,
                             const float* __restrict__ wg, const float* __restrict__ ww,
                             unsigned short* __restrict__ wq_b, unsigned short* __restrict__ wo_b,
                             unsigned short* __restrict__ wg_b, unsigned short* __restrict__ ww_b) {
    int r = blockIdx.x;
    int c4 = threadIdx.x * 4;
    if (r < 3072) {
        float4 v = *(const float4*)(wq + (size_t)r * Dc + c4);
        ushort4 o; o.x = f2b(v.x); o.y = f2b(v.y); o.z = f2b(v.z); o.w = f2b(v.w);
        *(ushort4*)(wq_b + (size_t)r * Dc + c4) = o;
    } else if (r < 4096) {
        int rr = r - 3072;
        float4 v = *(const float4*)(wo + (size_t)rr * Dc + c4);
        ushort4 o; o.x = f2b(v.x); o.y = f2b(v.y); o.z = f2b(v.z); o.w = f2b(v.w);
        *(ushort4*)(wo_b + (size_t)rr * Dc + c4) = o;
    } else if (r < 9600) {
        int rr = r - 4096;                // 0..Gp-1
        ushort4 o;
        if (rr < 2 * Fc) {
            int src = (rr >> 1) + (rr & 1) * Fc;
            float4 v = *(const float4*)(wg + (size_t)src * Dc + c4);
            o.x = f2b(v.x); o.y = f2b(v.y); o.z = f2b(v.z); o.w = f2b(v.w);
        } else {
            o.x = o.y = o.z = o.w = 0;
        }
        *(ushort4*)(wg_b + (size_t)rr * Dc + c4) = o;
    } else {
        int rr = r - 9600;                // 0..1023
        for (int c = threadIdx.x; c < Fp; c += 256) {
            float v = (c < Fc) ? ww[(size_t)rr * Fc + c] : 0.0f;
            ww_b[(size_t)rr * Fp + c] = f2b(v);
        }
    }
}

// ---------------- me_norm -> bf16 out ----------------
__global__ void k_menorm_b(const float* __restrict__ x, const float* __restrict__ w,
                           unsigned short* __restrict__ out) {
    int row = blockIdx.x;
    float4 v = ((const float4*)(x + (size_t)row * Dc))[threadIdx.x];
    float s = fabsf(v.x) + fabsf(v.y) + fabsf(v.z) + fabsf(v.w);
#pragma unroll
    for (int m = 32; m >= 1; m >>= 1) s += __shfl_xor(s, m);
    __shared__ float ws4[4];
    if ((threadIdx.x & 63) == 0) ws4[threadIdx.x >> 6] = s;
    __syncthreads();
    float tot = ws4[0] + ws4[1] + ws4[2] + ws4[3];
    float inv = 1.0f / (tot / (float)Dc + EPSc);
    float4 wv = ((const float4*)w)[threadIdx.x];
    ushort4 o;
    o.x = f2b(v.x * inv * wv.x);
    o.y = f2b(v.y * inv * wv.y);
    o.z = f2b(v.z * inv * wv.z);
    o.w = f2b(v.w * inv * wv.w);
    ((ushort4*)(out + (size_t)row * Dc))[threadIdx.x] = o;
}

// ---------------- MFMA GEMM, r11-pipelined 2-barrier tile (BM = 64 or 128) ----------------
// MODE 0: C=A@B^T (XCD swizzle). 1: +=Res. 2: qkv fused epilogue. 3: gate fused.
template <int MODE, int BM>
__global__ __launch_bounds__(256) void k_mfma_gemm(
    const unsigned short* __restrict__ A, const unsigned short* __restrict__ Bw,
    const float* __restrict__ Res, float* __restrict__ C,
    unsigned short* __restrict__ U0, unsigned short* __restrict__ U1,
    unsigned short* __restrict__ U2, int N, int K) {
    constexpr int MFR = BM / 32;          // A-frags / acc rows per wave (2 or 4)
    __shared__ __align__(16) unsigned short As[2][BM * 64];
    __shared__ __align__(16) unsigned short Bs[2][128 * 64];
    const int tid = threadIdx.x;
    const int lane = tid & 63;
    const int wid = tid >> 6;
    const int wr = wid >> 1, wc = wid & 1;
    const int l15 = lane & 15, g = lane >> 4;

    const int nwg = gridDim.x * gridDim.y;
    int w = blockIdx.y * gridDim.x + blockIdx.x;
    int f = (nwg & 7) ? w : ((w & 7) * (nwg >> 3) + (w >> 3));
    const int bm = (f % gridDim.x) * BM, bn = (f / gridDim.x) * 128;

    f32x4 acc[MFR][4] = {};
    const int nk = K >> 6;

#define STAGEL(buf, kt)                                                                          \
    {                                                                                            \
        _Pragma("unroll") for (int it = 0; it < MFR; ++it) {                                     \
            int ci = it * 256 + tid;                                                             \
            int r = ci >> 3, sc = (ci & 7) ^ (r & 7);                                            \
            __builtin_amdgcn_global_load_lds(                                                    \
                (const __attribute__((address_space(1))) void*)(A + (size_t)(bm + r) * K + (kt) * 64 + sc * 8), \
                (__attribute__((address_space(3))) void*)(&As[buf][ci * 8]), 16, 0, 0);          \
        }                                                                                        \
        _Pragma("unroll") for (int it = 0; it < 4; ++it) {                                       \
            int ci = it * 256 + tid;                                                             \
            int r = ci >> 3, sc = (ci & 7) ^ (r & 7);                                            \
            __builtin_amdgcn_global_load_lds(                                                    \
                (const __attribute__((address_space(1))) void*)(Bw + (size_t)(bn + r) * K + (kt) * 64 + sc * 8), \
                (__attribute__((address_space(3))) void*)(&Bs[buf][ci * 8]), 16, 0, 0);          \
        }                                                                                        \
    }

    STAGEL(0, 0);
    STAGEL(1, 1);
    if constexpr (BM == 128) { asm volatile("s_waitcnt vmcnt(8)" ::: "memory"); }
    else                     { asm volatile("s_waitcnt vmcnt(6)" ::: "memory"); }
    __builtin_amdgcn_s_barrier();

    for (int kt = 0; kt < nk; ++kt) {
        const int buf = kt & 1;
        const unsigned short* Ab = As[buf];
        const unsigned short* Bb = Bs[buf];
        bf16x8 bfr[4][2];
#pragma unroll
        for (int n = 0; n < 4; ++n) {
            int col = wc * 64 + n * 16 + l15;
#pragma unroll
            for (int kk = 0; kk < 2; ++kk) {
                int kc = kk * 4 + g;
                bfr[n][kk] = *(const bf16x8*)&Bb[(col * 8 + (kc ^ (col & 7))) * 8];
            }
        }
        bf16x8 af[MFR][2];
#pragma unroll
        for (int m = 0; m < MFR; ++m) {
            int row = wr * (BM / 2) + m * 16 + l15;
#pragma unroll
            for (int kk = 0; kk < 2; ++kk) {
                int kc = kk * 4 + g;
                af[m][kk] = *(const bf16x8*)&Ab[(row * 8 + (kc ^ (row & 7))) * 8];
            }
        }
        __builtin_amdgcn_s_setprio(1);
#pragma unroll
        for (int m = 0; m < MFR - 1; ++m)
#pragma unroll
            for (int kk = 0; kk < 2; ++kk)
#pragma unroll
                for (int n = 0; n < 4; ++n)
                    acc[m][n] = __builtin_amdgcn_mfma_f32_16x16x32_bf16(af[m][kk], bfr[n][kk], acc[m][n], 0, 0, 0);
        __builtin_amdgcn_s_setprio(0);
        asm volatile("s_waitcnt lgkmcnt(0)" ::: "memory");
        __builtin_amdgcn_s_barrier();
        if (kt + 2 < nk) STAGEL(buf, kt + 2);
        __builtin_amdgcn_s_setprio(1);
#pragma unroll
        for (int kk = 0; kk < 2; ++kk)
#pragma unroll
            for (int n = 0; n < 4; ++n)
                acc[MFR - 1][n] = __builtin_amdgcn_mfma_f32_16x16x32_bf16(af[MFR - 1][kk], bfr[n][kk], acc[MFR - 1][n], 0, 0, 0);
        __builtin_amdgcn_s_setprio(0);
        if (kt + 2 < nk) {
            if constexpr (BM == 128) { asm volatile("s_waitcnt vmcnt(8)" ::: "memory"); }
            else                     { asm volatile("s_waitcnt vmcnt(6)" ::: "memory"); }
        } else {
            asm volatile("s_waitcnt vmcnt(0)" ::: "memory");
        }
        __builtin_amdgcn_s_barrier();
    }
#undef STAGEL

    // epilogue: C/D mapping col = lane&15, row = (lane>>4)*4 + j  [m89-verified]
#pragma unroll
    for (int m = 0; m < MFR; ++m) {
        int row0 = bm + wr * (BM / 2) + m * 16 + (g << 2);
#pragma unroll
        for (int n = 0; n < 4; ++n) {
            int col = bn + wc * 64 + n * 16 + l15;
            if constexpr (MODE == 0 || MODE == 1) {
#pragma unroll
                for (int j = 0; j < 4; ++j) {
                    size_t idx = (size_t)(row0 + j) * N + col;
                    float v = acc[m][n][j];
                    if (MODE == 1) v += Res[idx];
                    C[idx] = v;
                }
            } else if constexpr (MODE == 2) {
                if (col < 2048) {
                    unsigned short* dst = (col < 1024) ? U0 : U1;
                    int hh = (col & 1023) >> 6, dh = col & 63;
#pragma unroll
                    for (int j = 0; j < 4; ++j) {
                        int row = row0 + j;
                        int b = row >> 10, t = row & 1023;
                        dst[((size_t)((b * Hc + hh) * Tc + t)) * 64 + dh] = f2b(acc[m][n][j]);
                    }
                } else {
                    int hh = (col >> 6) & 15, dh = col & 63;
                    int b = row0 >> 10, t = row0 & 1023;
                    ushort4 o4;
                    o4.x = f2b(acc[m][n][0]); o4.y = f2b(acc[m][n][1]);
                    o4.z = f2b(acc[m][n][2]); o4.w = f2b(acc[m][n][3]);
                    *(ushort4*)&U2[((size_t)((b * Hc + hh) * 64 + dh)) * Tc + t] = o4;
                }
            } else {  // MODE 3: gate
                float pv[4];
#pragma unroll
                for (int j = 0; j < 4; ++j) pv[j] = __shfl_xor(acc[m][n][j], 1);
                if ((l15 & 1) == 0) {
                    int fq = col >> 1;
#pragma unroll
                    for (int j = 0; j < 4; ++j) {
                        float gate = acc[m][n][j], val = pv[j];
                        float sigma = 0.5f * (gate / (fabsf(gate) + 1.0f) + 1.0f);
                        U0[(size_t)(row0 + j) * Fp + fq] = f2b(gate * sigma * val);
                    }
                }
            }
        }
    }
}

// ---------------- 256x256 GEMM, asymmetric-depth pipeline: A 2-deep, B 3-deep ----------------
// IDENTITY XCD map (A-panel 512KB L2-resident needs little lookahead; B is HBM/L3-cold and
// gets 2 FULL TILES of prefetch slack). LDS = 2x32KB A + 3x32KB B = 160KB (the full pool).
// Issue order per tile: A(kt+2) then B(kt+3); end-of-tile vmcnt(12) retires exactly A(kt+1)
// (B(kt+1) is 2 tiles old). Tail tiles drain with vmcnt(0). r19 lesson: launch_bounds stays
// (512,2) — tighter caps VGPR below the 128-reg accumulator and spills to scratch.
// GM 0: C = A@B^T fp32. GM 1: gate-fused epilogue -> G bf16 [2048][Fp].
template <int GM>
__global__ __launch_bounds__(512, 2) void k_gemm_8ph(
    const unsigned short* __restrict__ A, const unsigned short* __restrict__ Bw,
    float* __restrict__ C, unsigned short* __restrict__ G, int N, int K) {
    __shared__ __align__(16) unsigned short As[2][256 * 64];
    __shared__ __align__(16) unsigned short Bs[3][256 * 64];
    const int tid = threadIdx.x;
    const int lane = tid & 63, wid = tid >> 6;
    const int wm = wid >> 2, wn = wid & 3;
    const int l15 = lane & 15, g = lane >> 4;

    const int bm = blockIdx.x * 256;
    const int bn = blockIdx.y * 256;

    const int nk = K >> 6;
    f32x4 acc[8][4] = {};

#define STAGE_A8(slot, kt)                                                                       \
    {                                                                                            \
        _Pragma("unroll") for (int it = 0; it < 4; ++it) {                                       \
            int ci = it * 512 + tid;                                                             \
            int r = ci >> 3, c = (ci & 7) ^ (r & 7);                                             \
            __builtin_amdgcn_global_load_lds(                                                    \
                (const __attribute__((address_space(1))) void*)(A + (size_t)(bm + r) * K + (kt) * 64 + c * 8), \
                (__attribute__((address_space(3))) void*)(&As[slot][ci * 8]), 16, 0, 0);         \
        }                                                                                        \
    }
#define STAGE_B8(slot, kt)                                                                       \
    {                                                                                            \
        _Pragma("unroll") for (int it = 0; it < 4; ++it) {                                       \
            int ci = it * 512 + tid;                                                             \
            int r = ci >> 3, c = (ci & 7) ^ (r & 7);                                             \
            __builtin_amdgcn_global_load_lds(                                                    \
                (const __attribute__((address_space(1))) void*)(Bw + (size_t)(bn + r) * K + (kt) * 64 + c * 8), \
                (__attribute__((address_space(3))) void*)(&Bs[slot][ci * 8]), 16, 0, 0);         \
        }                                                                                        \
    }

    // prologue: A0,B0,A1,B1,B2 in flight (20 issues); vmcnt(12) retires A0,B0
    STAGE_A8(0, 0);
    STAGE_B8(0, 0);
    STAGE_A8(1, 1);
    STAGE_B8(1, 1);
    STAGE_B8(2, 2);
    asm volatile("s_waitcnt vmcnt(12)" ::: "memory");
    __builtin_amdgcn_s_barrier();

    int bslot = 0;                         // kt % 3, maintained incrementally
    for (int kt = 0; kt < nk; ++kt) {
        const int aslot = kt & 1;
        const unsigned short* Ab = As[aslot];
        const unsigned short* Bb = Bs[bslot];
        bf16x8 bfr[4][2];
#pragma unroll
        for (int n = 0; n < 4; ++n) {
            int col = wn * 64 + n * 16 + l15;
#pragma unroll
            for (int kk = 0; kk < 2; ++kk) {
                int kc = kk * 4 + g;
                bfr[n][kk] = *(const bf16x8*)&Bb[(col * 8 + (kc ^ (col & 7))) * 8];
            }
        }
        bf16x8 af[4][2][2];
#pragma unroll
        for (int p = 0; p < 4; ++p)
#pragma unroll
            for (int le = 0; le < 2; ++le) {
                int row = wm * 128 + (p * 2 + le) * 16 + l15;
#pragma unroll
                for (int kk = 0; kk < 2; ++kk) {
                    int kc = kk * 4 + g;
                    af[p][le][kk] = *(const bf16x8*)&Ab[(row * 8 + (kc ^ (row & 7))) * 8];
                }
            }
        __builtin_amdgcn_s_setprio(1);
#pragma unroll
        for (int p = 0; p < 3; ++p)
#pragma unroll
            for (int kk = 0; kk < 2; ++kk)
#pragma unroll
                for (int le = 0; le < 2; ++le)
#pragma unroll
                    for (int n = 0; n < 4; ++n)
                        acc[p * 2 + le][n] = __builtin_amdgcn_mfma_f32_16x16x32_bf16(
                            af[p][le][kk], bfr[n][kk], acc[p * 2 + le][n], 0, 0, 0);
        __builtin_amdgcn_s_setprio(0);
        // all reads of As[aslot]/Bs[bslot] complete in all waves -> safe to overwrite
        asm volatile("s_waitcnt lgkmcnt(0)" ::: "memory");
        __builtin_amdgcn_s_barrier();
        if (kt + 2 < nk) STAGE_A8(aslot, kt + 2);      // A first (retired by vmcnt(12))
        if (kt + 3 < nk) STAGE_B8(bslot, kt + 3);      // B second (2-tile slack)
        __builtin_amdgcn_s_setprio(1);
#pragma unroll
        for (int kk = 0; kk < 2; ++kk)
#pragma unroll
            for (int le = 0; le < 2; ++le)
#pragma unroll
                for (int n = 0; n < 4; ++n)
                    acc[6 + le][n] = __builtin_amdgcn_mfma_f32_16x16x32_bf16(
                        af[3][le][kk], bfr[n][kk], acc[6 + le][n], 0, 0, 0);
        __builtin_amdgcn_s_setprio(0);
        if (kt + 3 < nk) {
            asm volatile("s_waitcnt vmcnt(12)" ::: "memory");   // retires A(kt+1) (and older)
        } else {
            asm volatile("s_waitcnt vmcnt(0)" ::: "memory");    // tail drain
        }
        __builtin_amdgcn_s_barrier();
        bslot = (bslot == 2) ? 0 : bslot + 1;
    }
#undef STAGE_A8
#undef STAGE_B8

    // epilogue: C/D mapping col = lane&15, row = (lane>>4)*4 + j
#pragma unroll
    for (int m = 0; m < 8; ++m) {
        int row0 = bm + wm * 128 + m * 16 + (g << 2);
#pragma unroll
        for (int n = 0; n < 4; ++n) {
            int col = bn + wn * 64 + n * 16 + l15;
            if constexpr (GM == 0) {
#pragma unroll
                for (int j = 0; j < 4; ++j)
                    C[(size_t)(row0 + j) * N + col] = acc[m][n][j];
            } else {  // gate fusion: cols pair (2f, 2f+1) = (gate, val)
                float pv[4];
#pragma unroll
                for (int j = 0; j < 4; ++j) pv[j] = __shfl_xor(acc[m][n][j], 1);
                if ((l15 & 1) == 0) {
                    int fq = col >> 1;
                    if (fq < Fp) {
#pragma unroll
                        for (int j = 0; j < 4; ++j) {
                            float gate = acc[m][n][j], val = pv[j];
                            float sigma = 0.5f * (gate / (fabsf(gate) + 1.0f) + 1.0f);
                            G[(size_t)(row0 + j) * Fp + fq] = f2b(gate * sigma * val);
                        }
                    }
                }
            }
        }
    }
}

// ---------------- MFMA attention, KVBLK=128 (r15 version) ----------------
__global__ __launch_bounds__(256) void k_attn_mfma(
    const unsigned short* __restrict__ Qh, const unsigned short* __restrict__ Kh,
    const unsigned short* __restrict__ Vt, unsigned short* __restrict__ o) {
    const int d0 = blockIdx.x;
    const int r0 = d0 & 255;
    const int slot = d0 >> 8;
    const int bh = r0 >> 3;
    const int e = r0 & 7;
    const int bx = slot ? (15 - e) : e;
    const int q0 = bx * 64;
    const int b = bh >> 4, h = bh & 15;
    const float slope = exp2f(-0.5f * (float)(h + 1));

    __shared__ __align__(16) unsigned short Ks[128 * 64];
    __shared__ __align__(16) unsigned short Vs[64 * 128];
    __shared__ __align__(16) unsigned short Ps[4][16 * 128];

    const int tid = threadIdx.x, lane = tid & 63, wid = tid >> 6;
    const int q0w = q0 + wid * 16;
    const int l15 = lane & 15, g = lane >> 4;

    const unsigned short* qbase = Qh + ((size_t)(bh * Tc + q0w + l15)) * 64 + g * 8;
    bf16x8 qf[2];
    qf[0] = *(const bf16x8*)qbase;
    qf[1] = *(const bf16x8*)(qbase + 32);

    const int nt = (bx >> 1) + 1;

#define STAGE_K128(it)                                                                           \
    {                                                                                            \
        _Pragma("unroll") for (int i = 0; i < 4; ++i) {                                          \
            int ci = i * 256 + tid;                                                              \
            int r = ci >> 3, sc = (ci & 7) ^ (r & 7);                                            \
            __builtin_amdgcn_global_load_lds(                                                    \
                (const __attribute__((address_space(1))) void*)(Kh + ((size_t)(bh * Tc + (it) * 128 + r)) * 64 + sc * 8), \
                (__attribute__((address_space(3))) void*)(Ks + ci * 8), 16, 0, 0);               \
        }                                                                                        \
    }
#define STAGE_V128(it)                                                                           \
    {                                                                                            \
        _Pragma("unroll") for (int i = 0; i < 4; ++i) {                                          \
            int ci = i * 256 + tid;                                                              \
            int dh = ci >> 4, th = (ci >> 3) & 1, c = ci & 7;                                    \
            int sc = c ^ (dh & 7);                                                               \
            __builtin_amdgcn_global_load_lds(                                                    \
                (const __attribute__((address_space(1))) void*)(Vt + ((size_t)(bh * 64 + dh)) * Tc + (it) * 128 + th * 64 + sc * 8), \
                (__attribute__((address_space(3))) void*)(Vs + ci * 8), 16, 0, 0);               \
        }                                                                                        \
    }

    // ---------- pass A: exact row max ----------
    f32x4 mx = {-3e38f, -3e38f, -3e38f, -3e38f};
    for (int it = 0; it < nt; ++it) {
        const int st = it * 128;
        __syncthreads();
        STAGE_K128(it);
        __syncthreads();
#pragma unroll
        for (int si = 0; si < 8; ++si) {
            f32x4 d = {0.f, 0.f, 0.f, 0.f};
            int r2 = si * 16 + l15;
#pragma unroll
            for (int kc = 0; kc < 2; ++kc) {
                int c2 = kc * 4 + g;
                bf16x8 bk = *(const bf16x8*)&Ks[(r2 * 8 + (c2 ^ (r2 & 7))) * 8];
                d = __builtin_amdgcn_mfma_f32_16x16x32_bf16(qf[kc], bk, d, 0, 0, 0);
            }
            int s = st + r2;
#pragma unroll
            for (int j = 0; j < 4; ++j) {
                int t = q0w + g * 4 + j;
                float scv = (s <= t) ? d[j] * SCALEc - slope * (float)(t - s) : -3e38f;
                mx[j] = fmaxf(mx[j], scv);
            }
        }
    }
#pragma unroll
    for (int m = 8; m >= 1; m >>= 1)
#pragma unroll
        for (int j = 0; j < 4; ++j) mx[j] = fmaxf(mx[j], __shfl_xor(mx[j], m));

    // ---------- pass B: numerators, sum, PV ----------
    f32x4 sum = {0.f, 0.f, 0.f, 0.f};
    f32x4 oacc[4] = {};
    for (int it = 0; it < nt; ++it) {
        const int st = it * 128;
        __syncthreads();
        STAGE_K128(it);
        STAGE_V128(it);
        __syncthreads();
#pragma unroll
        for (int si = 0; si < 8; ++si) {
            f32x4 d = {0.f, 0.f, 0.f, 0.f};
            int sl = si * 16 + l15;
#pragma unroll
            for (int kc = 0; kc < 2; ++kc) {
                int c2 = kc * 4 + g;
                bf16x8 bk = *(const bf16x8*)&Ks[(sl * 8 + (c2 ^ (sl & 7))) * 8];
                d = __builtin_amdgcn_mfma_f32_16x16x32_bf16(qf[kc], bk, d, 0, 0, 0);
            }
            int s = st + sl;
            int chunk = sl >> 3, coff = sl & 7;
#pragma unroll
            for (int j = 0; j < 4; ++j) {
                int t = q0w + g * 4 + j;
                int q = g * 4 + j;
                unsigned short pb = 0;
                if (s <= t) {
                    float sv = d[j] * SCALEc - slope * (float)(t - s) - mx[j];
                    float num = __builtin_amdgcn_rcpf(fmaf(0.5f * sv, sv, 1.0f - sv));
                    sum[j] += num;
                    pb = f2b(num);
                }
                Ps[wid][q * 128 + ((chunk & 8) | ((chunk & 7) ^ (q & 7))) * 8 + coff] = pb;
            }
        }
        __syncthreads();
#pragma unroll
        for (int kc2 = 0; kc2 < 4; ++kc2) {
            int c2 = kc2 * 4 + g;
            bf16x8 pa = *(const bf16x8*)&Ps[wid][(l15 * 16 + ((c2 & 8) | ((c2 & 7) ^ (l15 & 7)))) * 8];
#pragma unroll
            for (int n = 0; n < 4; ++n) {
                int r2 = n * 16 + l15;
                bf16x8 vb = *(const bf16x8*)&Vs[(r2 * 16 + ((c2 & 8) | ((c2 & 7) ^ (r2 & 7)))) * 8];
                oacc[n] = __builtin_amdgcn_mfma_f32_16x16x32_bf16(pa, vb, oacc[n], 0, 0, 0);
            }
        }
    }
#undef STAGE_K128
#undef STAGE_V128
#pragma unroll
    for (int m = 8; m >= 1; m >>= 1)
#pragma unroll
        for (int j = 0; j < 4; ++j) sum[j] += __shfl_xor(sum[j], m);

#pragma unroll
    for (int j = 0; j < 4; ++j) {
        int t = q0w + g * 4 + j;
        float svm = NEGc - mx[j];
        float mnum = __builtin_amdgcn_rcpf(fmaf(0.5f * svm, svm, 1.0f - svm));
        float inv = __builtin_amdgcn_rcpf(sum[j] + (float)(Tc - 1 - t) * mnum + EPSc);
#pragma unroll
        for (int n = 0; n < 4; ++n) {
            o[((size_t)(b * Tc + t)) * Dc + h * 64 + n * 16 + l15] = f2b(oacc[n][j] * inv);
        }
    }
}

extern "C" void kernel_launch(void* const* d_in, const int* in_sizes, int n_in,
                              void* d_out, int out_size, void* d_ws, size_t ws_size,
                              hipStream_t stream) {
    const int* ids = (const int*)d_in[0];
    const float* embed_w = (const float*)d_in[1];
    const float* qkv_w = (const float*)d_in[2];
    const float* out_w = (const float*)d_in[3];
    const float* gate_w = (const float*)d_in[4];
    const float* wout_w = (const float*)d_in[5];
    const float* n1 = (const float*)d_in[6];
    const float* n2 = (const float*)d_in[7];
    const float* nf = (const float*)d_in[8];
    float* outp = (float*)d_out;

    char* ws = (char*)d_ws;
    float* x = (float*)(ws + 0);                                   //  8,388,608
    unsigned short* h = (unsigned short*)(ws + 8388608);           //  4,194,304 (h / o share)
    unsigned short* Qh = (unsigned short*)(ws + 12582912);         //  4,194,304
    unsigned short* Kh = (unsigned short*)(ws + 16777216);         //  4,194,304
    unsigned short* Vt = (unsigned short*)(ws + 20971520);         //  4,194,304
    unsigned short* g = (unsigned short*)(ws + 25165824);          // 11,272,192
    unsigned short* w1 = (unsigned short*)(ws + 36438016);         //  6,291,456 (wq)
    unsigned short* wo_b = (unsigned short*)(ws + 42729472);       //  2,097,152
    unsigned short* wg_b = (unsigned short*)(ws + 44826624);       // 11,272,192 (end 56,098,816; gate GEMM
                                                                   //   over-reads 256KB into ww_b, discarded)
    unsigned short* ww_b = (unsigned short*)(ws + 56098816);       //  5,636,096 (end 61,734,912)
    unsigned short* emb_b = (unsigned short*)(ws + 12582912);      // 65,536,000 overlay (end 78,118,912)

    dim3 blk(256);

    k_embed<<<dim3(Mc), blk, 0, stream>>>(ids, embed_w, x);

    for (int l = 0; l < 4; l++) {
        const float* wq = qkv_w + (size_t)l * 3 * Dc * Dc;
        const float* wo = out_w + (size_t)l * Dc * Dc;
        const float* wg = gate_w + (size_t)l * 2 * Fc * Dc;
        const float* ww = wout_w + (size_t)l * Dc * Fc;

        // all weight conversions in ONE kernel
        k_conv_layer<<<dim3(10624), blk, 0, stream>>>(wq, wo, wg, ww, w1, wo_b, wg_b, ww_b);

        // h = me_norm(x, n1) -> bf16
        k_menorm_b<<<dim3(Mc), blk, 0, stream>>>(x, n1 + (size_t)l * Dc, h);
        // qkv GEMM fused: writes Qh, Kh, Vt directly (N=3072, K=1024)
        k_mfma_gemm<2, 128><<<dim3(16, 24), blk, 0, stream>>>(h, w1, nullptr, nullptr, Qh, Kh, Vt, 3 * Dc, Dc);
        // attention -> o (bf16, into h buffer); KVBLK=128, balanced 1D grid
        k_attn_mfma<<<dim3(512), blk, 0, stream>>>(Qh, Kh, Vt, h);
        // x = x + o @ wo^T  (N=1024, K=1024), BM=64 -> 256 wgs
        k_mfma_gemm<1, 64><<<dim3(32, 8), blk, 0, stream>>>(h, wo_b, x, x, nullptr, nullptr, nullptr, Dc, Dc);
        // h = me_norm(x, n2)
        k_menorm_b<<<dim3(Mc), blk, 0, stream>>>(x, n2 + (size_t)l * Dc, h);
        // gate GEMM fused via 256^2 pipeline (grid 8x22 covers N=5632; cols >= 5504 discarded)
        k_gemm_8ph<1><<<dim3(8, 22), dim3(512), 0, stream>>>(h, wg_b, nullptr, g, Gp, Dc);
        // x = x + g @ ww^T  (N=1024, K=2752 padded), BM=64 -> 256 wgs
        k_mfma_gemm<1, 64><<<dim3(32, 8), blk, 0, stream>>>(g, ww_b, x, x, nullptr, nullptr, nullptr, Dc, Fp);
    }

    // final norm + logits
    k_menorm_b<<<dim3(Mc), blk, 0, stream>>>(x, nf, h);
    k_conv<<<dim3(32000), blk, 0, stream>>>(embed_w, emb_b);
    // logits = h @ embed^T  (N=32000, K=1024) — A 2-deep / B 3-deep pipeline, identity XCD map
    k_gemm_8ph<0><<<dim3(8, 125), dim3(512), 0, stream>>>(h, emb_b, outp, nullptr, 32000, Dc);
}

// Round 22
// 929.767 us; speedup vs baseline: 1.0098x; 1.0098x over previous
//
#include <hip/hip_runtime.h>
#include <math.h>

typedef __attribute__((ext_vector_type(8))) short bf16x8;
typedef __attribute__((ext_vector_type(4))) float f32x4;

namespace {
constexpr int Bc = 2, Tc = 1024, Dc = 1024, Hc = 16, Fc = 2730;
constexpr int Fp = 2752;   // padded F (K of wout GEMM)
constexpr int Gp = 5504;   // padded 2F (N of gate GEMM)
constexpr int Mc = Bc * Tc;               // 2048 rows
constexpr float EPSc = 1e-6f;
constexpr float NEGc = -10000.0f;
constexpr float SCALEc = 0.125f;          // 1/sqrt(64)
}

// fp32 -> bf16 RTNE (finite values only, which holds here)
__device__ __forceinline__ unsigned short f2b(float f) {
    unsigned int u = __float_as_uint(f);
    u += 0x7FFFu + ((u >> 16) & 1u);
    return (unsigned short)(u >> 16);
}

// ---------------- embedding gather (fp32 x) ----------------
__global__ void k_embed(const int* __restrict__ ids, const float* __restrict__ ew,
                        float* __restrict__ x) {
    int row = blockIdx.x;
    int id = ids[row];
    const float4* src = (const float4*)(ew + (size_t)id * Dc);
    float4* dst = (float4*)(x + (size_t)row * Dc);
    dst[threadIdx.x] = src[threadIdx.x];
}

// ---------------- straight fp32 -> bf16 convert, rows of 1024 (embedding) ----------------
__global__ void k_conv(const float* __restrict__ in, unsigned short* __restrict__ out) {
    size_t i = ((size_t)blockIdx.x * 256 + threadIdx.x) * 4;
    float4 v = *(const float4*)(in + i);
    ushort4 o;
    o.x = f2b(v.x); o.y = f2b(v.y); o.z = f2b(v.z); o.w = f2b(v.w);
    *(ushort4*)(out + i) = o;
}

// ---------------- fused per-layer weight convert (wq | wo | wg-interleave | ww-padk) ----------------
__global__ void k_conv_layer(const float* __restrict__ wq, const float* __restrict__ wo,
                             const float* __restrict__ wg, const float* __restrict__ ww,
                             unsigned short* __restrict__ wq_b, unsigned short* __restrict__ wo_b,
                             unsigned short* __restrict__ wg_b, unsigned short* __restrict__ ww_b) {
    int r = blockIdx.x;
    int c4 = threadIdx.x * 4;
    if (r < 3072) {
        float4 v = *(const float4*)(wq + (size_t)r * Dc + c4);
        ushort4 o; o.x = f2b(v.x); o.y = f2b(v.y); o.z = f2b(v.z); o.w = f2b(v.w);
        *(ushort4*)(wq_b + (size_t)r * Dc + c4) = o;
    } else if (r < 4096) {
        int rr = r - 3072;
        float4 v = *(const float4*)(wo + (size_t)rr * Dc + c4);
        ushort4 o; o.x = f2b(v.x); o.y = f2b(v.y); o.z = f2b(v.z); o.w = f2b(v.w);
        *(ushort4*)(wo_b + (size_t)rr * Dc + c4) = o;
    } else if (r < 9600) {
        int rr = r - 4096;                // 0..Gp-1
        ushort4 o;
        if (rr < 2 * Fc) {
            int src = (rr >> 1) + (rr & 1) * Fc;
            float4 v = *(const float4*)(wg + (size_t)src * Dc + c4);
            o.x = f2b(v.x); o.y = f2b(v.y); o.z = f2b(v.z); o.w = f2b(v.w);
        } else {
            o.x = o.y = o.z = o.w = 0;
        }
        *(ushort4*)(wg_b + (size_t)rr * Dc + c4) = o;
    } else {
        int rr = r - 9600;                // 0..1023
        for (int c = threadIdx.x; c < Fp; c += 256) {
            float v = (c < Fc) ? ww[(size_t)rr * Fc + c] : 0.0f;
            ww_b[(size_t)rr * Fp + c] = f2b(v);
        }
    }
}

// ---------------- me_norm -> bf16 out ----------------
__global__ void k_menorm_b(const float* __restrict__ x, const float* __restrict__ w,
                           unsigned short* __restrict__ out) {
    int row = blockIdx.x;
    float4 v = ((const float4*)(x + (size_t)row * Dc))[threadIdx.x];
    float s = fabsf(v.x) + fabsf(v.y) + fabsf(v.z) + fabsf(v.w);
#pragma unroll
    for (int m = 32; m >= 1; m >>= 1) s += __shfl_xor(s, m);
    __shared__ float ws4[4];
    if ((threadIdx.x & 63) == 0) ws4[threadIdx.x >> 6] = s;
    __syncthreads();
    float tot = ws4[0] + ws4[1] + ws4[2] + ws4[3];
    float inv = 1.0f / (tot / (float)Dc + EPSc);
    float4 wv = ((const float4*)w)[threadIdx.x];
    ushort4 o;
    o.x = f2b(v.x * inv * wv.x);
    o.y = f2b(v.y * inv * wv.y);
    o.z = f2b(v.z * inv * wv.z);
    o.w = f2b(v.w * inv * wv.w);
    ((ushort4*)(out + (size_t)row * Dc))[threadIdx.x] = o;
}

// ---------------- MFMA GEMM, r11-pipelined 2-barrier tile (BM = 64 or 128) ----------------
// MODE 0: C=A@B^T (XCD swizzle). 1: +=Res. 2: qkv fused epilogue. 3: gate fused.
template <int MODE, int BM>
__global__ __launch_bounds__(256) void k_mfma_gemm(
    const unsigned short* __restrict__ A, const unsigned short* __restrict__ Bw,
    const float* __restrict__ Res, float* __restrict__ C,
    unsigned short* __restrict__ U0, unsigned short* __restrict__ U1,
    unsigned short* __restrict__ U2, int N, int K) {
    constexpr int MFR = BM / 32;          // A-frags / acc rows per wave (2 or 4)
    __shared__ __align__(16) unsigned short As[2][BM * 64];
    __shared__ __align__(16) unsigned short Bs[2][128 * 64];
    const int tid = threadIdx.x;
    const int lane = tid & 63;
    const int wid = tid >> 6;
    const int wr = wid >> 1, wc = wid & 1;
    const int l15 = lane & 15, g = lane >> 4;

    const int nwg = gridDim.x * gridDim.y;
    int w = blockIdx.y * gridDim.x + blockIdx.x;
    int f = (nwg & 7) ? w : ((w & 7) * (nwg >> 3) + (w >> 3));
    const int bm = (f % gridDim.x) * BM, bn = (f / gridDim.x) * 128;

    f32x4 acc[MFR][4] = {};
    const int nk = K >> 6;

#define STAGEL(buf, kt)                                                                          \
    {                                                                                            \
        _Pragma("unroll") for (int it = 0; it < MFR; ++it) {                                     \
            int ci = it * 256 + tid;                                                             \
            int r = ci >> 3, sc = (ci & 7) ^ (r & 7);                                            \
            __builtin_amdgcn_global_load_lds(                                                    \
                (const __attribute__((address_space(1))) void*)(A + (size_t)(bm + r) * K + (kt) * 64 + sc * 8), \
                (__attribute__((address_space(3))) void*)(&As[buf][ci * 8]), 16, 0, 0);          \
        }                                                                                        \
        _Pragma("unroll") for (int it = 0; it < 4; ++it) {                                       \
            int ci = it * 256 + tid;                                                             \
            int r = ci >> 3, sc = (ci & 7) ^ (r & 7);                                            \
            __builtin_amdgcn_global_load_lds(                                                    \
                (const __attribute__((address_space(1))) void*)(Bw + (size_t)(bn + r) * K + (kt) * 64 + sc * 8), \
                (__attribute__((address_space(3))) void*)(&Bs[buf][ci * 8]), 16, 0, 0);          \
        }                                                                                        \
    }

    STAGEL(0, 0);
    STAGEL(1, 1);
    if constexpr (BM == 128) { asm volatile("s_waitcnt vmcnt(8)" ::: "memory"); }
    else                     { asm volatile("s_waitcnt vmcnt(6)" ::: "memory"); }
    __builtin_amdgcn_s_barrier();

    for (int kt = 0; kt < nk; ++kt) {
        const int buf = kt & 1;
        const unsigned short* Ab = As[buf];
        const unsigned short* Bb = Bs[buf];
        bf16x8 bfr[4][2];
#pragma unroll
        for (int n = 0; n < 4; ++n) {
            int col = wc * 64 + n * 16 + l15;
#pragma unroll
            for (int kk = 0; kk < 2; ++kk) {
                int kc = kk * 4 + g;
                bfr[n][kk] = *(const bf16x8*)&Bb[(col * 8 + (kc ^ (col & 7))) * 8];
            }
        }
        bf16x8 af[MFR][2];
#pragma unroll
        for (int m = 0; m < MFR; ++m) {
            int row = wr * (BM / 2) + m * 16 + l15;
#pragma unroll
            for (int kk = 0; kk < 2; ++kk) {
                int kc = kk * 4 + g;
                af[m][kk] = *(const bf16x8*)&Ab[(row * 8 + (kc ^ (row & 7))) * 8];
            }
        }
        __builtin_amdgcn_s_setprio(1);
#pragma unroll
        for (int m = 0; m < MFR - 1; ++m)
#pragma unroll
            for (int kk = 0; kk < 2; ++kk)
#pragma unroll
                for (int n = 0; n < 4; ++n)
                    acc[m][n] = __builtin_amdgcn_mfma_f32_16x16x32_bf16(af[m][kk], bfr[n][kk], acc[m][n], 0, 0, 0);
        __builtin_amdgcn_s_setprio(0);
        asm volatile("s_waitcnt lgkmcnt(0)" ::: "memory");
        __builtin_amdgcn_s_barrier();
        if (kt + 2 < nk) STAGEL(buf, kt + 2);
        __builtin_amdgcn_s_setprio(1);
#pragma unroll
        for (int kk = 0; kk < 2; ++kk)
#pragma unroll
            for (int n = 0; n < 4; ++n)
                acc[MFR - 1][n] = __builtin_amdgcn_mfma_f32_16x16x32_bf16(af[MFR - 1][kk], bfr[n][kk], acc[MFR - 1][n], 0, 0, 0);
        __builtin_amdgcn_s_setprio(0);
        if (kt + 2 < nk) {
            if constexpr (BM == 128) { asm volatile("s_waitcnt vmcnt(8)" ::: "memory"); }
            else                     { asm volatile("s_waitcnt vmcnt(6)" ::: "memory"); }
        } else {
            asm volatile("s_waitcnt vmcnt(0)" ::: "memory");
        }
        __builtin_amdgcn_s_barrier();
    }
#undef STAGEL

    // epilogue: C/D mapping col = lane&15, row = (lane>>4)*4 + j  [m89-verified]
#pragma unroll
    for (int m = 0; m < MFR; ++m) {
        int row0 = bm + wr * (BM / 2) + m * 16 + (g << 2);
#pragma unroll
        for (int n = 0; n < 4; ++n) {
            int col = bn + wc * 64 + n * 16 + l15;
            if constexpr (MODE == 0 || MODE == 1) {
#pragma unroll
                for (int j = 0; j < 4; ++j) {
                    size_t idx = (size_t)(row0 + j) * N + col;
                    float v = acc[m][n][j];
                    if (MODE == 1) v += Res[idx];
                    C[idx] = v;
                }
            } else if constexpr (MODE == 2) {
                if (col < 2048) {
                    unsigned short* dst = (col < 1024) ? U0 : U1;
                    int hh = (col & 1023) >> 6, dh = col & 63;
#pragma unroll
                    for (int j = 0; j < 4; ++j) {
                        int row = row0 + j;
                        int b = row >> 10, t = row & 1023;
                        dst[((size_t)((b * Hc + hh) * Tc + t)) * 64 + dh] = f2b(acc[m][n][j]);
                    }
                } else {
                    int hh = (col >> 6) & 15, dh = col & 63;
                    int b = row0 >> 10, t = row0 & 1023;
                    ushort4 o4;
                    o4.x = f2b(acc[m][n][0]); o4.y = f2b(acc[m][n][1]);
                    o4.z = f2b(acc[m][n][2]); o4.w = f2b(acc[m][n][3]);
                    *(ushort4*)&U2[((size_t)((b * Hc + hh) * 64 + dh)) * Tc + t] = o4;
                }
            } else {  // MODE 3: gate
                float pv[4];
#pragma unroll
                for (int j = 0; j < 4; ++j) pv[j] = __shfl_xor(acc[m][n][j], 1);
                if ((l15 & 1) == 0) {
                    int fq = col >> 1;
#pragma unroll
                    for (int j = 0; j < 4; ++j) {
                        float gate = acc[m][n][j], val = pv[j];
                        float sigma = 0.5f * (gate / (fabsf(gate) + 1.0f) + 1.0f);
                        U0[(size_t)(row0 + j) * Fp + fq] = f2b(gate * sigma * val);
                    }
                }
            }
        }
    }
}

// ---------------- 256x256 GEMM, pipelined 2-barrier tile (r20 exact, 170us on logits) ----------------
// IDENTITY XCD map. GM 0: C = A@B^T fp32. GM 1: gate-fused epilogue -> G bf16 [2048][Fp].
// r19 lesson: launch_bounds stays (512,2). r21 lesson: deeper B-prefetch is neutral
// (not VMEM-latency-bound; LDS-read-throughput + lockstep structure is the ceiling here).
template <int GM>
__global__ __launch_bounds__(512, 2) void k_gemm_8ph(
    const unsigned short* __restrict__ A, const unsigned short* __restrict__ Bw,
    float* __restrict__ C, unsigned short* __restrict__ G, int N, int K) {
    __shared__ __align__(16) unsigned short As[2][256 * 64];
    __shared__ __align__(16) unsigned short Bs[2][256 * 64];
    const int tid = threadIdx.x;
    const int lane = tid & 63, wid = tid >> 6;
    const int wm = wid >> 2, wn = wid & 3;
    const int l15 = lane & 15, g = lane >> 4;

    const int bm = blockIdx.x * 256;
    const int bn = blockIdx.y * 256;

    const int nk = K >> 6;
    f32x4 acc[8][4] = {};

#define STAGE8(buf, kt)                                                                          \
    {                                                                                            \
        _Pragma("unroll") for (int it = 0; it < 4; ++it) {                                       \
            int ci = it * 512 + tid;                                                             \
            int r = ci >> 3, c = (ci & 7) ^ (r & 7);                                             \
            __builtin_amdgcn_global_load_lds(                                                    \
                (const __attribute__((address_space(1))) void*)(A + (size_t)(bm + r) * K + (kt) * 64 + c * 8), \
                (__attribute__((address_space(3))) void*)(&As[buf][ci * 8]), 16, 0, 0);          \
        }                                                                                        \
        _Pragma("unroll") for (int it = 0; it < 4; ++it) {                                       \
            int ci = it * 512 + tid;                                                             \
            int r = ci >> 3, c = (ci & 7) ^ (r & 7);                                             \
            __builtin_amdgcn_global_load_lds(                                                    \
                (const __attribute__((address_space(1))) void*)(Bw + (size_t)(bn + r) * K + (kt) * 64 + c * 8), \
                (__attribute__((address_space(3))) void*)(&Bs[buf][ci * 8]), 16, 0, 0);          \
        }                                                                                        \
    }

    STAGE8(0, 0);
    STAGE8(1, 1);
    asm volatile("s_waitcnt vmcnt(8)" ::: "memory");
    __builtin_amdgcn_s_barrier();

    for (int kt = 0; kt < nk; ++kt) {
        const int buf = kt & 1;
        const unsigned short* Ab = As[buf];
        const unsigned short* Bb = Bs[buf];
        bf16x8 bfr[4][2];
#pragma unroll
        for (int n = 0; n < 4; ++n) {
            int col = wn * 64 + n * 16 + l15;
#pragma unroll
            for (int kk = 0; kk < 2; ++kk) {
                int kc = kk * 4 + g;
                bfr[n][kk] = *(const bf16x8*)&Bb[(col * 8 + (kc ^ (col & 7))) * 8];
            }
        }
        bf16x8 af[4][2][2];
#pragma unroll
        for (int p = 0; p < 4; ++p)
#pragma unroll
            for (int le = 0; le < 2; ++le) {
                int row = wm * 128 + (p * 2 + le) * 16 + l15;
#pragma unroll
                for (int kk = 0; kk < 2; ++kk) {
                    int kc = kk * 4 + g;
                    af[p][le][kk] = *(const bf16x8*)&Ab[(row * 8 + (kc ^ (row & 7))) * 8];
                }
            }
        __builtin_amdgcn_s_setprio(1);
#pragma unroll
        for (int p = 0; p < 3; ++p)
#pragma unroll
            for (int kk = 0; kk < 2; ++kk)
#pragma unroll
                for (int le = 0; le < 2; ++le)
#pragma unroll
                    for (int n = 0; n < 4; ++n)
                        acc[p * 2 + le][n] = __builtin_amdgcn_mfma_f32_16x16x32_bf16(
                            af[p][le][kk], bfr[n][kk], acc[p * 2 + le][n], 0, 0, 0);
        __builtin_amdgcn_s_setprio(0);
        asm volatile("s_waitcnt lgkmcnt(0)" ::: "memory");
        __builtin_amdgcn_s_barrier();
        if (kt + 2 < nk) STAGE8(buf, kt + 2);
        __builtin_amdgcn_s_setprio(1);
#pragma unroll
        for (int kk = 0; kk < 2; ++kk)
#pragma unroll
            for (int le = 0; le < 2; ++le)
#pragma unroll
                for (int n = 0; n < 4; ++n)
                    acc[6 + le][n] = __builtin_amdgcn_mfma_f32_16x16x32_bf16(
                        af[3][le][kk], bfr[n][kk], acc[6 + le][n], 0, 0, 0);
        __builtin_amdgcn_s_setprio(0);
        if (kt + 2 < nk) {
            asm volatile("s_waitcnt vmcnt(8)" ::: "memory");
        } else {
            asm volatile("s_waitcnt vmcnt(0)" ::: "memory");
        }
        __builtin_amdgcn_s_barrier();
    }
#undef STAGE8

    // epilogue: C/D mapping col = lane&15, row = (lane>>4)*4 + j
#pragma unroll
    for (int m = 0; m < 8; ++m) {
        int row0 = bm + wm * 128 + m * 16 + (g << 2);
#pragma unroll
        for (int n = 0; n < 4; ++n) {
            int col = bn + wn * 64 + n * 16 + l15;
            if constexpr (GM == 0) {
#pragma unroll
                for (int j = 0; j < 4; ++j)
                    C[(size_t)(row0 + j) * N + col] = acc[m][n][j];
            } else {  // gate fusion: cols pair (2f, 2f+1) = (gate, val)
                float pv[4];
#pragma unroll
                for (int j = 0; j < 4; ++j) pv[j] = __shfl_xor(acc[m][n][j], 1);
                if ((l15 & 1) == 0) {
                    int fq = col >> 1;
                    if (fq < Fp) {
#pragma unroll
                        for (int j = 0; j < 4; ++j) {
                            float gate = acc[m][n][j], val = pv[j];
                            float sigma = 0.5f * (gate / (fabsf(gate) + 1.0f) + 1.0f);
                            G[(size_t)(row0 + j) * Fp + fq] = f2b(gate * sigma * val);
                        }
                    }
                }
            }
        }
    }
}

// ---------------- MFMA attention, KVBLK=128 + DOUBLE-BUFFERED staging ----------------
// 8ph pattern ported: stage(it+1) issued before compute(it); counted vmcnt (4 pass A /
// 8 pass B, never 0 mid-loop); ending __syncthreads drains lgkm before buffer overwrite.
// LDS 80KB (Ks dbuf 32 + Vs dbuf 32 + Ps 16); grid 512 -> 2 blocks/CU unchanged (2x80=160KB).
__global__ __launch_bounds__(256) void k_attn_mfma(
    const unsigned short* __restrict__ Qh, const unsigned short* __restrict__ Kh,
    const unsigned short* __restrict__ Vt, unsigned short* __restrict__ o) {
    const int d0 = blockIdx.x;
    const int r0 = d0 & 255;
    const int slot = d0 >> 8;
    const int bh = r0 >> 3;
    const int e = r0 & 7;
    const int bx = slot ? (15 - e) : e;
    const int q0 = bx * 64;
    const int b = bh >> 4, h = bh & 15;
    const float slope = exp2f(-0.5f * (float)(h + 1));

    __shared__ __align__(16) unsigned short Ks[2][128 * 64];
    __shared__ __align__(16) unsigned short Vs[2][64 * 128];
    __shared__ __align__(16) unsigned short Ps[4][16 * 128];

    const int tid = threadIdx.x, lane = tid & 63, wid = tid >> 6;
    const int q0w = q0 + wid * 16;
    const int l15 = lane & 15, g = lane >> 4;

    const unsigned short* qbase = Qh + ((size_t)(bh * Tc + q0w + l15)) * 64 + g * 8;
    bf16x8 qf[2];
    qf[0] = *(const bf16x8*)qbase;
    qf[1] = *(const bf16x8*)(qbase + 32);

    const int nt = (bx >> 1) + 1;

#define STAGE_K128(kb, it)                                                                       \
    {                                                                                            \
        _Pragma("unroll") for (int i = 0; i < 4; ++i) {                                          \
            int ci = i * 256 + tid;                                                              \
            int r = ci >> 3, sc = (ci & 7) ^ (r & 7);                                            \
            __builtin_amdgcn_global_load_lds(                                                    \
                (const __attribute__((address_space(1))) void*)(Kh + ((size_t)(bh * Tc + (it) * 128 + r)) * 64 + sc * 8), \
                (__attribute__((address_space(3))) void*)(&Ks[kb][ci * 8]), 16, 0, 0);           \
        }                                                                                        \
    }
#define STAGE_V128(kb, it)                                                                       \
    {                                                                                            \
        _Pragma("unroll") for (int i = 0; i < 4; ++i) {                                          \
            int ci = i * 256 + tid;                                                              \
            int dh = ci >> 4, th = (ci >> 3) & 1, c = ci & 7;                                    \
            int sc = c ^ (dh & 7);                                                               \
            __builtin_amdgcn_global_load_lds(                                                    \
                (const __attribute__((address_space(1))) void*)(Vt + ((size_t)(bh * 64 + dh)) * Tc + (it) * 128 + th * 64 + sc * 8), \
                (__attribute__((address_space(3))) void*)(&Vs[kb][ci * 8]), 16, 0, 0);           \
        }                                                                                        \
    }

    // ---------- pass A: exact row max (double-buffered K staging) ----------
    f32x4 mx = {-3e38f, -3e38f, -3e38f, -3e38f};
    STAGE_K128(0, 0);
    for (int it = 0; it < nt; ++it) {
        const int kb = it & 1;
        if (it + 1 < nt) {
            STAGE_K128(kb ^ 1, it + 1);
            asm volatile("s_waitcnt vmcnt(4)" ::: "memory");   // stage(it) landed; (it+1) in flight
        } else {
            asm volatile("s_waitcnt vmcnt(0)" ::: "memory");
        }
        __builtin_amdgcn_s_barrier();
        const int st = it * 128;
#pragma unroll
        for (int si = 0; si < 8; ++si) {
            f32x4 d = {0.f, 0.f, 0.f, 0.f};
            int r2 = si * 16 + l15;
#pragma unroll
            for (int kc = 0; kc < 2; ++kc) {
                int c2 = kc * 4 + g;
                bf16x8 bk = *(const bf16x8*)&Ks[kb][(r2 * 8 + (c2 ^ (r2 & 7))) * 8];
                d = __builtin_amdgcn_mfma_f32_16x16x32_bf16(qf[kc], bk, d, 0, 0, 0);
            }
            int s = st + r2;
#pragma unroll
            for (int j = 0; j < 4; ++j) {
                int t = q0w + g * 4 + j;
                float scv = (s <= t) ? d[j] * SCALEc - slope * (float)(t - s) : -3e38f;
                mx[j] = fmaxf(mx[j], scv);
            }
        }
        __syncthreads();   // all reads of Ks[kb] done before its overwrite next iter
    }
#pragma unroll
    for (int m = 8; m >= 1; m >>= 1)
#pragma unroll
        for (int j = 0; j < 4; ++j) mx[j] = fmaxf(mx[j], __shfl_xor(mx[j], m));

    // ---------- pass B: numerators, sum, PV (double-buffered K+V staging) ----------
    f32x4 sum = {0.f, 0.f, 0.f, 0.f};
    f32x4 oacc[4] = {};
    STAGE_K128(0, 0);
    STAGE_V128(0, 0);
    for (int it = 0; it < nt; ++it) {
        const int kb = it & 1;
        if (it + 1 < nt) {
            STAGE_K128(kb ^ 1, it + 1);
            STAGE_V128(kb ^ 1, it + 1);
            asm volatile("s_waitcnt vmcnt(8)" ::: "memory");   // stage(it) landed; (it+1) in flight
        } else {
            asm volatile("s_waitcnt vmcnt(0)" ::: "memory");
        }
        __builtin_amdgcn_s_barrier();
        const int st = it * 128;
#pragma unroll
        for (int si = 0; si < 8; ++si) {
            f32x4 d = {0.f, 0.f, 0.f, 0.f};
            int sl = si * 16 + l15;
#pragma unroll
            for (int kc = 0; kc < 2; ++kc) {
                int c2 = kc * 4 + g;
                bf16x8 bk = *(const bf16x8*)&Ks[kb][(sl * 8 + (c2 ^ (sl & 7))) * 8];
                d = __builtin_amdgcn_mfma_f32_16x16x32_bf16(qf[kc], bk, d, 0, 0, 0);
            }
            int s = st + sl;
            int chunk = sl >> 3, coff = sl & 7;
#pragma unroll
            for (int j = 0; j < 4; ++j) {
                int t = q0w + g * 4 + j;
                int q = g * 4 + j;
                unsigned short pb = 0;
                if (s <= t) {
                    float sv = d[j] * SCALEc - slope * (float)(t - s) - mx[j];
                    float num = __builtin_amdgcn_rcpf(fmaf(0.5f * sv, sv, 1.0f - sv));
                    sum[j] += num;
                    pb = f2b(num);
                }
                Ps[wid][q * 128 + ((chunk & 8) | ((chunk & 7) ^ (q & 7))) * 8 + coff] = pb;
            }
        }
        __syncthreads();
#pragma unroll
        for (int kc2 = 0; kc2 < 4; ++kc2) {
            int c2 = kc2 * 4 + g;
            bf16x8 pa = *(const bf16x8*)&Ps[wid][(l15 * 16 + ((c2 & 8) | ((c2 & 7) ^ (l15 & 7)))) * 8];
#pragma unroll
            for (int n = 0; n < 4; ++n) {
                int r2 = n * 16 + l15;
                bf16x8 vb = *(const bf16x8*)&Vs[kb][(r2 * 16 + ((c2 & 8) | ((c2 & 7) ^ (r2 & 7)))) * 8];
                oacc[n] = __builtin_amdgcn_mfma_f32_16x16x32_bf16(pa, vb, oacc[n], 0, 0, 0);
            }
        }
        __syncthreads();   // all reads of Ks/Vs[kb] done before overwrite next iter
    }
#undef STAGE_K128
#undef STAGE_V128
#pragma unroll
    for (int m = 8; m >= 1; m >>= 1)
#pragma unroll
        for (int j = 0; j < 4; ++j) sum[j] += __shfl_xor(sum[j], m);

#pragma unroll
    for (int j = 0; j < 4; ++j) {
        int t = q0w + g * 4 + j;
        float svm = NEGc - mx[j];
        float mnum = __builtin_amdgcn_rcpf(fmaf(0.5f * svm, svm, 1.0f - svm));
        float inv = __builtin_amdgcn_rcpf(sum[j] + (float)(Tc - 1 - t) * mnum + EPSc);
#pragma unroll
        for (int n = 0; n < 4; ++n) {
            o[((size_t)(b * Tc + t)) * Dc + h * 64 + n * 16 + l15] = f2b(oacc[n][j] * inv);
        }
    }
}

extern "C" void kernel_launch(void* const* d_in, const int* in_sizes, int n_in,
                              void* d_out, int out_size, void* d_ws, size_t ws_size,
                              hipStream_t stream) {
    const int* ids = (const int*)d_in[0];
    const float* embed_w = (const float*)d_in[1];
    const float* qkv_w = (const float*)d_in[2];
    const float* out_w = (const float*)d_in[3];
    const float* gate_w = (const float*)d_in[4];
    const float* wout_w = (const float*)d_in[5];
    const float* n1 = (const float*)d_in[6];
    const float* n2 = (const float*)d_in[7];
    const float* nf = (const float*)d_in[8];
    float* outp = (float*)d_out;

    char* ws = (char*)d_ws;
    float* x = (float*)(ws + 0);                                   //  8,388,608
    unsigned short* h = (unsigned short*)(ws + 8388608);           //  4,194,304 (h / o share)
    unsigned short* Qh = (unsigned short*)(ws + 12582912);         //  4,194,304
    unsigned short* Kh = (unsigned short*)(ws + 16777216);         //  4,194,304
    unsigned short* Vt = (unsigned short*)(ws + 20971520);         //  4,194,304
    unsigned short* g = (unsigned short*)(ws + 25165824);          // 11,272,192
    unsigned short* w1 = (unsigned short*)(ws + 36438016);         //  6,291,456 (wq)
    unsigned short* wo_b = (unsigned short*)(ws + 42729472);       //  2,097,152
    unsigned short* wg_b = (unsigned short*)(ws + 44826624);       // 11,272,192 (end 56,098,816; gate GEMM
                                                                   //   over-reads 256KB into ww_b, discarded)
    unsigned short* ww_b = (unsigned short*)(ws + 56098816);       //  5,636,096 (end 61,734,912)
    unsigned short* emb_b = (unsigned short*)(ws + 12582912);      // 65,536,000 overlay (end 78,118,912)

    dim3 blk(256);

    k_embed<<<dim3(Mc), blk, 0, stream>>>(ids, embed_w, x);

    for (int l = 0; l < 4; l++) {
        const float* wq = qkv_w + (size_t)l * 3 * Dc * Dc;
        const float* wo = out_w + (size_t)l * Dc * Dc;
        const float* wg = gate_w + (size_t)l * 2 * Fc * Dc;
        const float* ww = wout_w + (size_t)l * Dc * Fc;

        // all weight conversions in ONE kernel
        k_conv_layer<<<dim3(10624), blk, 0, stream>>>(wq, wo, wg, ww, w1, wo_b, wg_b, ww_b);

        // h = me_norm(x, n1) -> bf16
        k_menorm_b<<<dim3(Mc), blk, 0, stream>>>(x, n1 + (size_t)l * Dc, h);
        // qkv GEMM fused: writes Qh, Kh, Vt directly (N=3072, K=1024)
        k_mfma_gemm<2, 128><<<dim3(16, 24), blk, 0, stream>>>(h, w1, nullptr, nullptr, Qh, Kh, Vt, 3 * Dc, Dc);
        // attention -> o (bf16, into h buffer); KVBLK=128, double-buffered staging
        k_attn_mfma<<<dim3(512), blk, 0, stream>>>(Qh, Kh, Vt, h);
        // x = x + o @ wo^T  (N=1024, K=1024), BM=64 -> 256 wgs
        k_mfma_gemm<1, 64><<<dim3(32, 8), blk, 0, stream>>>(h, wo_b, x, x, nullptr, nullptr, nullptr, Dc, Dc);
        // h = me_norm(x, n2)
        k_menorm_b<<<dim3(Mc), blk, 0, stream>>>(x, n2 + (size_t)l * Dc, h);
        // gate GEMM fused via 256^2 8ph (grid 8x22 covers N=5632; cols >= 5504 discarded)
        k_gemm_8ph<1><<<dim3(8, 22), dim3(512), 0, stream>>>(h, wg_b, nullptr, g, Gp, Dc);
        // x = x + g @ ww^T  (N=1024, K=2752 padded), BM=64 -> 256 wgs
        k_mfma_gemm<1, 64><<<dim3(32, 8), blk, 0, stream>>>(g, ww_b, x, x, nullptr, nullptr, nullptr, Dc, Fp);
    }

    // final norm + logits
    k_menorm_b<<<dim3(Mc), blk, 0, stream>>>(x, nf, h);
    k_conv<<<dim3(32000), blk, 0, stream>>>(embed_w, emb_b);
    // logits = h @ embed^T  (N=32000, K=1024) — r20 pipelined 256^2, identity XCD map
    k_gemm_8ph<0><<<dim3(8, 125), dim3(512), 0, stream>>>(h, emb_b, outp, nullptr, 32000, Dc);
}

// Round 23
// 917.281 us; speedup vs baseline: 1.0236x; 1.0136x over previous
//
#include <hip/hip_runtime.h>
#include <math.h>

typedef __attribute__((ext_vector_type(8))) short bf16x8;
typedef __attribute__((ext_vector_type(4))) float f32x4;

namespace {
constexpr int Bc = 2, Tc = 1024, Dc = 1024, Hc = 16, Fc = 2730;
constexpr int Fp = 2752;   // padded F (K of wout GEMM)
constexpr int Gp = 5504;   // padded 2F (N of gate GEMM)
constexpr int Mc = Bc * Tc;               // 2048 rows
constexpr float EPSc = 1e-6f;
constexpr float NEGc = -10000.0f;
constexpr float SCALEc = 0.125f;          // 1/sqrt(64)
}

// fp32 -> bf16 RTNE (finite values only, which holds here)
__device__ __forceinline__ unsigned short f2b(float f) {
    unsigned int u = __float_as_uint(f);
    u += 0x7FFFu + ((u >> 16) & 1u);
    return (unsigned short)(u >> 16);
}

// ---------------- embedding gather (fp32 x) ----------------
__global__ void k_embed(const int* __restrict__ ids, const float* __restrict__ ew,
                        float* __restrict__ x) {
    int row = blockIdx.x;
    int id = ids[row];
    const float4* src = (const float4*)(ew + (size_t)id * Dc);
    float4* dst = (float4*)(x + (size_t)row * Dc);
    dst[threadIdx.x] = src[threadIdx.x];
}

// ---------------- me_norm body (shared by fused kernels) ----------------
__device__ __forceinline__ void menorm_row(const float* __restrict__ x, const float* __restrict__ w,
                                           unsigned short* __restrict__ out, int row) {
    float4 v = ((const float4*)(x + (size_t)row * Dc))[threadIdx.x];
    float s = fabsf(v.x) + fabsf(v.y) + fabsf(v.z) + fabsf(v.w);
#pragma unroll
    for (int m = 32; m >= 1; m >>= 1) s += __shfl_xor(s, m);
    __shared__ float ws4[4];
    if ((threadIdx.x & 63) == 0) ws4[threadIdx.x >> 6] = s;
    __syncthreads();
    float tot = ws4[0] + ws4[1] + ws4[2] + ws4[3];
    float inv = 1.0f / (tot / (float)Dc + EPSc);
    float4 wv = ((const float4*)w)[threadIdx.x];
    ushort4 o;
    o.x = f2b(v.x * inv * wv.x);
    o.y = f2b(v.y * inv * wv.y);
    o.z = f2b(v.z * inv * wv.z);
    o.w = f2b(v.w * inv * wv.w);
    ((ushort4*)(out + (size_t)row * Dc))[threadIdx.x] = o;
}

// ---------------- me_norm standalone (n2 path) ----------------
__global__ void k_menorm_b(const float* __restrict__ x, const float* __restrict__ w,
                           unsigned short* __restrict__ out) {
    menorm_row(x, w, out, blockIdx.x);
}

// ---------------- fused per-layer: weight convert (wq|wo|wg-ilv|ww-padk) + menorm1 ----------------
// grid 12672: [0,3072) wq; [3072,4096) wo; [4096,9600) wg interleaved; [9600,10624) ww padk;
// [10624,12672) menorm1 rows (independent of the weight conversions).
__global__ void k_conv_layer(const float* __restrict__ wq, const float* __restrict__ wo,
                             const float* __restrict__ wg, const float* __restrict__ ww,
                             unsigned short* __restrict__ wq_b, unsigned short* __restrict__ wo_b,
                             unsigned short* __restrict__ wg_b, unsigned short* __restrict__ ww_b,
                             const float* __restrict__ x, const float* __restrict__ n1,
                             unsigned short* __restrict__ h) {
    int r = blockIdx.x;
    int c4 = threadIdx.x * 4;
    if (r < 3072) {
        float4 v = *(const float4*)(wq + (size_t)r * Dc + c4);
        ushort4 o; o.x = f2b(v.x); o.y = f2b(v.y); o.z = f2b(v.z); o.w = f2b(v.w);
        *(ushort4*)(wq_b + (size_t)r * Dc + c4) = o;
    } else if (r < 4096) {
        int rr = r - 3072;
        float4 v = *(const float4*)(wo + (size_t)rr * Dc + c4);
        ushort4 o; o.x = f2b(v.x); o.y = f2b(v.y); o.z = f2b(v.z); o.w = f2b(v.w);
        *(ushort4*)(wo_b + (size_t)rr * Dc + c4) = o;
    } else if (r < 9600) {
        int rr = r - 4096;                // 0..Gp-1
        ushort4 o;
        if (rr < 2 * Fc) {
            int src = (rr >> 1) + (rr & 1) * Fc;
            float4 v = *(const float4*)(wg + (size_t)src * Dc + c4);
            o.x = f2b(v.x); o.y = f2b(v.y); o.z = f2b(v.z); o.w = f2b(v.w);
        } else {
            o.x = o.y = o.z = o.w = 0;
        }
        *(ushort4*)(wg_b + (size_t)rr * Dc + c4) = o;
    } else if (r < 10624) {
        int rr = r - 9600;                // 0..1023
        for (int c = threadIdx.x; c < Fp; c += 256) {
            float v = (c < Fc) ? ww[(size_t)rr * Fc + c] : 0.0f;
            ww_b[(size_t)rr * Fp + c] = f2b(v);
        }
    } else {
        menorm_row(x, n1, h, r - 10624);  // 0..2047
    }
}

// ---------------- fused final: embedding convert + final menorm ----------------
// grid 34048: [0,32000) embed rows -> emb_b; [32000,34048) menorm(x, nf) -> h.
__global__ void k_conv_final(const float* __restrict__ ew, unsigned short* __restrict__ emb_b,
                             const float* __restrict__ x, const float* __restrict__ nf,
                             unsigned short* __restrict__ h) {
    int r = blockIdx.x;
    if (r < 32000) {
        size_t i = (size_t)r * Dc + threadIdx.x * 4;
        float4 v = *(const float4*)(ew + i);
        ushort4 o;
        o.x = f2b(v.x); o.y = f2b(v.y); o.z = f2b(v.z); o.w = f2b(v.w);
        *(ushort4*)(emb_b + i) = o;
    } else {
        menorm_row(x, nf, h, r - 32000);
    }
}

// ---------------- MFMA GEMM, r11-pipelined 2-barrier tile (BM = 64 or 128) ----------------
// MODE 0: C=A@B^T (XCD swizzle). 1: +=Res. 2: qkv fused epilogue. 3: gate fused.
template <int MODE, int BM>
__global__ __launch_bounds__(256) void k_mfma_gemm(
    const unsigned short* __restrict__ A, const unsigned short* __restrict__ Bw,
    const float* __restrict__ Res, float* __restrict__ C,
    unsigned short* __restrict__ U0, unsigned short* __restrict__ U1,
    unsigned short* __restrict__ U2, int N, int K) {
    constexpr int MFR = BM / 32;          // A-frags / acc rows per wave (2 or 4)
    __shared__ __align__(16) unsigned short As[2][BM * 64];
    __shared__ __align__(16) unsigned short Bs[2][128 * 64];
    const int tid = threadIdx.x;
    const int lane = tid & 63;
    const int wid = tid >> 6;
    const int wr = wid >> 1, wc = wid & 1;
    const int l15 = lane & 15, g = lane >> 4;

    const int nwg = gridDim.x * gridDim.y;
    int w = blockIdx.y * gridDim.x + blockIdx.x;
    int f = (nwg & 7) ? w : ((w & 7) * (nwg >> 3) + (w >> 3));
    const int bm = (f % gridDim.x) * BM, bn = (f / gridDim.x) * 128;

    f32x4 acc[MFR][4] = {};
    const int nk = K >> 6;

#define STAGEL(buf, kt)                                                                          \
    {                                                                                            \
        _Pragma("unroll") for (int it = 0; it < MFR; ++it) {                                     \
            int ci = it * 256 + tid;                                                             \
            int r = ci >> 3, sc = (ci & 7) ^ (r & 7);                                            \
            __builtin_amdgcn_global_load_lds(                                                    \
                (const __attribute__((address_space(1))) void*)(A + (size_t)(bm + r) * K + (kt) * 64 + sc * 8), \
                (__attribute__((address_space(3))) void*)(&As[buf][ci * 8]), 16, 0, 0);          \
        }                                                                                        \
        _Pragma("unroll") for (int it = 0; it < 4; ++it) {                                       \
            int ci = it * 256 + tid;                                                             \
            int r = ci >> 3, sc = (ci & 7) ^ (r & 7);                                            \
            __builtin_amdgcn_global_load_lds(                                                    \
                (const __attribute__((address_space(1))) void*)(Bw + (size_t)(bn + r) * K + (kt) * 64 + sc * 8), \
                (__attribute__((address_space(3))) void*)(&Bs[buf][ci * 8]), 16, 0, 0);          \
        }                                                                                        \
    }

    STAGEL(0, 0);
    STAGEL(1, 1);
    if constexpr (BM == 128) { asm volatile("s_waitcnt vmcnt(8)" ::: "memory"); }
    else                     { asm volatile("s_waitcnt vmcnt(6)" ::: "memory"); }
    __builtin_amdgcn_s_barrier();

    for (int kt = 0; kt < nk; ++kt) {
        const int buf = kt & 1;
        const unsigned short* Ab = As[buf];
        const unsigned short* Bb = Bs[buf];
        bf16x8 bfr[4][2];
#pragma unroll
        for (int n = 0; n < 4; ++n) {
            int col = wc * 64 + n * 16 + l15;
#pragma unroll
            for (int kk = 0; kk < 2; ++kk) {
                int kc = kk * 4 + g;
                bfr[n][kk] = *(const bf16x8*)&Bb[(col * 8 + (kc ^ (col & 7))) * 8];
            }
        }
        bf16x8 af[MFR][2];
#pragma unroll
        for (int m = 0; m < MFR; ++m) {
            int row = wr * (BM / 2) + m * 16 + l15;
#pragma unroll
            for (int kk = 0; kk < 2; ++kk) {
                int kc = kk * 4 + g;
                af[m][kk] = *(const bf16x8*)&Ab[(row * 8 + (kc ^ (row & 7))) * 8];
            }
        }
        __builtin_amdgcn_s_setprio(1);
#pragma unroll
        for (int m = 0; m < MFR - 1; ++m)
#pragma unroll
            for (int kk = 0; kk < 2; ++kk)
#pragma unroll
                for (int n = 0; n < 4; ++n)
                    acc[m][n] = __builtin_amdgcn_mfma_f32_16x16x32_bf16(af[m][kk], bfr[n][kk], acc[m][n], 0, 0, 0);
        __builtin_amdgcn_s_setprio(0);
        asm volatile("s_waitcnt lgkmcnt(0)" ::: "memory");
        __builtin_amdgcn_s_barrier();
        if (kt + 2 < nk) STAGEL(buf, kt + 2);
        __builtin_amdgcn_s_setprio(1);
#pragma unroll
        for (int kk = 0; kk < 2; ++kk)
#pragma unroll
            for (int n = 0; n < 4; ++n)
                acc[MFR - 1][n] = __builtin_amdgcn_mfma_f32_16x16x32_bf16(af[MFR - 1][kk], bfr[n][kk], acc[MFR - 1][n], 0, 0, 0);
        __builtin_amdgcn_s_setprio(0);
        if (kt + 2 < nk) {
            if constexpr (BM == 128) { asm volatile("s_waitcnt vmcnt(8)" ::: "memory"); }
            else                     { asm volatile("s_waitcnt vmcnt(6)" ::: "memory"); }
        } else {
            asm volatile("s_waitcnt vmcnt(0)" ::: "memory");
        }
        __builtin_amdgcn_s_barrier();
    }
#undef STAGEL

    // epilogue: C/D mapping col = lane&15, row = (lane>>4)*4 + j  [m89-verified]
#pragma unroll
    for (int m = 0; m < MFR; ++m) {
        int row0 = bm + wr * (BM / 2) + m * 16 + (g << 2);
#pragma unroll
        for (int n = 0; n < 4; ++n) {
            int col = bn + wc * 64 + n * 16 + l15;
            if constexpr (MODE == 0 || MODE == 1) {
#pragma unroll
                for (int j = 0; j < 4; ++j) {
                    size_t idx = (size_t)(row0 + j) * N + col;
                    float v = acc[m][n][j];
                    if (MODE == 1) v += Res[idx];
                    C[idx] = v;
                }
            } else if constexpr (MODE == 2) {
                if (col < 2048) {
                    unsigned short* dst = (col < 1024) ? U0 : U1;
                    int hh = (col & 1023) >> 6, dh = col & 63;
#pragma unroll
                    for (int j = 0; j < 4; ++j) {
                        int row = row0 + j;
                        int b = row >> 10, t = row & 1023;
                        dst[((size_t)((b * Hc + hh) * Tc + t)) * 64 + dh] = f2b(acc[m][n][j]);
                    }
                } else {
                    int hh = (col >> 6) & 15, dh = col & 63;
                    int b = row0 >> 10, t = row0 & 1023;
                    ushort4 o4;
                    o4.x = f2b(acc[m][n][0]); o4.y = f2b(acc[m][n][1]);
                    o4.z = f2b(acc[m][n][2]); o4.w = f2b(acc[m][n][3]);
                    *(ushort4*)&U2[((size_t)((b * Hc + hh) * 64 + dh)) * Tc + t] = o4;
                }
            } else {  // MODE 3: gate
                float pv[4];
#pragma unroll
                for (int j = 0; j < 4; ++j) pv[j] = __shfl_xor(acc[m][n][j], 1);
                if ((l15 & 1) == 0) {
                    int fq = col >> 1;
#pragma unroll
                    for (int j = 0; j < 4; ++j) {
                        float gate = acc[m][n][j], val = pv[j];
                        float sigma = 0.5f * (gate / (fabsf(gate) + 1.0f) + 1.0f);
                        U0[(size_t)(row0 + j) * Fp + fq] = f2b(gate * sigma * val);
                    }
                }
            }
        }
    }
}

// ---------------- 256x256 GEMM, pipelined 2-barrier tile (r20 exact, ~170us on logits) ----------------
// IDENTITY XCD map. GM 0: C = A@B^T fp32. GM 1: gate-fused epilogue -> G bf16 [2048][Fp].
// r19 lesson: launch_bounds stays (512,2). r21 lesson: deeper B-prefetch neutral (structure-bound).
template <int GM>
__global__ __launch_bounds__(512, 2) void k_gemm_8ph(
    const unsigned short* __restrict__ A, const unsigned short* __restrict__ Bw,
    float* __restrict__ C, unsigned short* __restrict__ G, int N, int K) {
    __shared__ __align__(16) unsigned short As[2][256 * 64];
    __shared__ __align__(16) unsigned short Bs[2][256 * 64];
    const int tid = threadIdx.x;
    const int lane = tid & 63, wid = tid >> 6;
    const int wm = wid >> 2, wn = wid & 3;
    const int l15 = lane & 15, g = lane >> 4;

    const int bm = blockIdx.x * 256;
    const int bn = blockIdx.y * 256;

    const int nk = K >> 6;
    f32x4 acc[8][4] = {};

#define STAGE8(buf, kt)                                                                          \
    {                                                                                            \
        _Pragma("unroll") for (int it = 0; it < 4; ++it) {                                       \
            int ci = it * 512 + tid;                                                             \
            int r = ci >> 3, c = (ci & 7) ^ (r & 7);                                             \
            __builtin_amdgcn_global_load_lds(                                                    \
                (const __attribute__((address_space(1))) void*)(A + (size_t)(bm + r) * K + (kt) * 64 + c * 8), \
                (__attribute__((address_space(3))) void*)(&As[buf][ci * 8]), 16, 0, 0);          \
        }                                                                                        \
        _Pragma("unroll") for (int it = 0; it < 4; ++it) {                                       \
            int ci = it * 512 + tid;                                                             \
            int r = ci >> 3, c = (ci & 7) ^ (r & 7);                                             \
            __builtin_amdgcn_global_load_lds(                                                    \
                (const __attribute__((address_space(1))) void*)(Bw + (size_t)(bn + r) * K + (kt) * 64 + c * 8), \
                (__attribute__((address_space(3))) void*)(&Bs[buf][ci * 8]), 16, 0, 0);          \
        }                                                                                        \
    }

    STAGE8(0, 0);
    STAGE8(1, 1);
    asm volatile("s_waitcnt vmcnt(8)" ::: "memory");
    __builtin_amdgcn_s_barrier();

    for (int kt = 0; kt < nk; ++kt) {
        const int buf = kt & 1;
        const unsigned short* Ab = As[buf];
        const unsigned short* Bb = Bs[buf];
        bf16x8 bfr[4][2];
#pragma unroll
        for (int n = 0; n < 4; ++n) {
            int col = wn * 64 + n * 16 + l15;
#pragma unroll
            for (int kk = 0; kk < 2; ++kk) {
                int kc = kk * 4 + g;
                bfr[n][kk] = *(const bf16x8*)&Bb[(col * 8 + (kc ^ (col & 7))) * 8];
            }
        }
        bf16x8 af[4][2][2];
#pragma unroll
        for (int p = 0; p < 4; ++p)
#pragma unroll
            for (int le = 0; le < 2; ++le) {
                int row = wm * 128 + (p * 2 + le) * 16 + l15;
#pragma unroll
                for (int kk = 0; kk < 2; ++kk) {
                    int kc = kk * 4 + g;
                    af[p][le][kk] = *(const bf16x8*)&Ab[(row * 8 + (kc ^ (row & 7))) * 8];
                }
            }
        __builtin_amdgcn_s_setprio(1);
#pragma unroll
        for (int p = 0; p < 3; ++p)
#pragma unroll
            for (int kk = 0; kk < 2; ++kk)
#pragma unroll
                for (int le = 0; le < 2; ++le)
#pragma unroll
                    for (int n = 0; n < 4; ++n)
                        acc[p * 2 + le][n] = __builtin_amdgcn_mfma_f32_16x16x32_bf16(
                            af[p][le][kk], bfr[n][kk], acc[p * 2 + le][n], 0, 0, 0);
        __builtin_amdgcn_s_setprio(0);
        asm volatile("s_waitcnt lgkmcnt(0)" ::: "memory");
        __builtin_amdgcn_s_barrier();
        if (kt + 2 < nk) STAGE8(buf, kt + 2);
        __builtin_amdgcn_s_setprio(1);
#pragma unroll
        for (int kk = 0; kk < 2; ++kk)
#pragma unroll
            for (int le = 0; le < 2; ++le)
#pragma unroll
                for (int n = 0; n < 4; ++n)
                    acc[6 + le][n] = __builtin_amdgcn_mfma_f32_16x16x32_bf16(
                        af[3][le][kk], bfr[n][kk], acc[6 + le][n], 0, 0, 0);
        __builtin_amdgcn_s_setprio(0);
        if (kt + 2 < nk) {
            asm volatile("s_waitcnt vmcnt(8)" ::: "memory");
        } else {
            asm volatile("s_waitcnt vmcnt(0)" ::: "memory");
        }
        __builtin_amdgcn_s_barrier();
    }
#undef STAGE8

    // epilogue: C/D mapping col = lane&15, row = (lane>>4)*4 + j
#pragma unroll
    for (int m = 0; m < 8; ++m) {
        int row0 = bm + wm * 128 + m * 16 + (g << 2);
#pragma unroll
        for (int n = 0; n < 4; ++n) {
            int col = bn + wn * 64 + n * 16 + l15;
            if constexpr (GM == 0) {
#pragma unroll
                for (int j = 0; j < 4; ++j)
                    C[(size_t)(row0 + j) * N + col] = acc[m][n][j];
            } else {  // gate fusion: cols pair (2f, 2f+1) = (gate, val)
                float pv[4];
#pragma unroll
                for (int j = 0; j < 4; ++j) pv[j] = __shfl_xor(acc[m][n][j], 1);
                if ((l15 & 1) == 0) {
                    int fq = col >> 1;
                    if (fq < Fp) {
#pragma unroll
                        for (int j = 0; j < 4; ++j) {
                            float gate = acc[m][n][j], val = pv[j];
                            float sigma = 0.5f * (gate / (fabsf(gate) + 1.0f) + 1.0f);
                            G[(size_t)(row0 + j) * Fp + fq] = f2b(gate * sigma * val);
                        }
                    }
                }
            }
        }
    }
}

// ---------------- MFMA attention, KVBLK=128 + double-buffered staging (r22, proven) ----------------
__global__ __launch_bounds__(256) void k_attn_mfma(
    const unsigned short* __restrict__ Qh, const unsigned short* __restrict__ Kh,
    const unsigned short* __restrict__ Vt, unsigned short* __restrict__ o) {
    const int d0 = blockIdx.x;
    const int r0 = d0 & 255;
    const int slot = d0 >> 8;
    const int bh = r0 >> 3;
    const int e = r0 & 7;
    const int bx = slot ? (15 - e) : e;
    const int q0 = bx * 64;
    const int b = bh >> 4, h = bh & 15;
    const float slope = exp2f(-0.5f * (float)(h + 1));

    __shared__ __align__(16) unsigned short Ks[2][128 * 64];
    __shared__ __align__(16) unsigned short Vs[2][64 * 128];
    __shared__ __align__(16) unsigned short Ps[4][16 * 128];

    const int tid = threadIdx.x, lane = tid & 63, wid = tid >> 6;
    const int q0w = q0 + wid * 16;
    const int l15 = lane & 15, g = lane >> 4;

    const unsigned short* qbase = Qh + ((size_t)(bh * Tc + q0w + l15)) * 64 + g * 8;
    bf16x8 qf[2];
    qf[0] = *(const bf16x8*)qbase;
    qf[1] = *(const bf16x8*)(qbase + 32);

    const int nt = (bx >> 1) + 1;

#define STAGE_K128(kb, it)                                                                       \
    {                                                                                            \
        _Pragma("unroll") for (int i = 0; i < 4; ++i) {                                          \
            int ci = i * 256 + tid;                                                              \
            int r = ci >> 3, sc = (ci & 7) ^ (r & 7);                                            \
            __builtin_amdgcn_global_load_lds(                                                    \
                (const __attribute__((address_space(1))) void*)(Kh + ((size_t)(bh * Tc + (it) * 128 + r)) * 64 + sc * 8), \
                (__attribute__((address_space(3))) void*)(&Ks[kb][ci * 8]), 16, 0, 0);           \
        }                                                                                        \
    }
#define STAGE_V128(kb, it)                                                                       \
    {                                                                                            \
        _Pragma("unroll") for (int i = 0; i < 4; ++i) {                                          \
            int ci = i * 256 + tid;                                                              \
            int dh = ci >> 4, th = (ci >> 3) & 1, c = ci & 7;                                    \
            int sc = c ^ (dh & 7);                                                               \
            __builtin_amdgcn_global_load_lds(                                                    \
                (const __attribute__((address_space(1))) void*)(Vt + ((size_t)(bh * 64 + dh)) * Tc + (it) * 128 + th * 64 + sc * 8), \
                (__attribute__((address_space(3))) void*)(&Vs[kb][ci * 8]), 16, 0, 0);           \
        }                                                                                        \
    }

    // ---------- pass A: exact row max (double-buffered K staging) ----------
    f32x4 mx = {-3e38f, -3e38f, -3e38f, -3e38f};
    STAGE_K128(0, 0);
    for (int it = 0; it < nt; ++it) {
        const int kb = it & 1;
        if (it + 1 < nt) {
            STAGE_K128(kb ^ 1, it + 1);
            asm volatile("s_waitcnt vmcnt(4)" ::: "memory");
        } else {
            asm volatile("s_waitcnt vmcnt(0)" ::: "memory");
        }
        __builtin_amdgcn_s_barrier();
        const int st = it * 128;
#pragma unroll
        for (int si = 0; si < 8; ++si) {
            f32x4 d = {0.f, 0.f, 0.f, 0.f};
            int r2 = si * 16 + l15;
#pragma unroll
            for (int kc = 0; kc < 2; ++kc) {
                int c2 = kc * 4 + g;
                bf16x8 bk = *(const bf16x8*)&Ks[kb][(r2 * 8 + (c2 ^ (r2 & 7))) * 8];
                d = __builtin_amdgcn_mfma_f32_16x16x32_bf16(qf[kc], bk, d, 0, 0, 0);
            }
            int s = st + r2;
#pragma unroll
            for (int j = 0; j < 4; ++j) {
                int t = q0w + g * 4 + j;
                float scv = (s <= t) ? d[j] * SCALEc - slope * (float)(t - s) : -3e38f;
                mx[j] = fmaxf(mx[j], scv);
            }
        }
        __syncthreads();
    }
#pragma unroll
    for (int m = 8; m >= 1; m >>= 1)
#pragma unroll
        for (int j = 0; j < 4; ++j) mx[j] = fmaxf(mx[j], __shfl_xor(mx[j], m));

    // ---------- pass B: numerators, sum, PV (double-buffered K+V staging) ----------
    f32x4 sum = {0.f, 0.f, 0.f, 0.f};
    f32x4 oacc[4] = {};
    STAGE_K128(0, 0);
    STAGE_V128(0, 0);
    for (int it = 0; it < nt; ++it) {
        const int kb = it & 1;
        if (it + 1 < nt) {
            STAGE_K128(kb ^ 1, it + 1);
            STAGE_V128(kb ^ 1, it + 1);
            asm volatile("s_waitcnt vmcnt(8)" ::: "memory");
        } else {
            asm volatile("s_waitcnt vmcnt(0)" ::: "memory");
        }
        __builtin_amdgcn_s_barrier();
        const int st = it * 128;
#pragma unroll
        for (int si = 0; si < 8; ++si) {
            f32x4 d = {0.f, 0.f, 0.f, 0.f};
            int sl = si * 16 + l15;
#pragma unroll
            for (int kc = 0; kc < 2; ++kc) {
                int c2 = kc * 4 + g;
                bf16x8 bk = *(const bf16x8*)&Ks[kb][(sl * 8 + (c2 ^ (sl & 7))) * 8];
                d = __builtin_amdgcn_mfma_f32_16x16x32_bf16(qf[kc], bk, d, 0, 0, 0);
            }
            int s = st + sl;
            int chunk = sl >> 3, coff = sl & 7;
#pragma unroll
            for (int j = 0; j < 4; ++j) {
                int t = q0w + g * 4 + j;
                int q = g * 4 + j;
                unsigned short pb = 0;
                if (s <= t) {
                    float sv = d[j] * SCALEc - slope * (float)(t - s) - mx[j];
                    float num = __builtin_amdgcn_rcpf(fmaf(0.5f * sv, sv, 1.0f - sv));
                    sum[j] += num;
                    pb = f2b(num);
                }
                Ps[wid][q * 128 + ((chunk & 8) | ((chunk & 7) ^ (q & 7))) * 8 + coff] = pb;
            }
        }
        __syncthreads();
#pragma unroll
        for (int kc2 = 0; kc2 < 4; ++kc2) {
            int c2 = kc2 * 4 + g;
            bf16x8 pa = *(const bf16x8*)&Ps[wid][(l15 * 16 + ((c2 & 8) | ((c2 & 7) ^ (l15 & 7)))) * 8];
#pragma unroll
            for (int n = 0; n < 4; ++n) {
                int r2 = n * 16 + l15;
                bf16x8 vb = *(const bf16x8*)&Vs[kb][(r2 * 16 + ((c2 & 8) | ((c2 & 7) ^ (r2 & 7)))) * 8];
                oacc[n] = __builtin_amdgcn_mfma_f32_16x16x32_bf16(pa, vb, oacc[n], 0, 0, 0);
            }
        }
        __syncthreads();
    }
#undef STAGE_K128
#undef STAGE_V128
#pragma unroll
    for (int m = 8; m >= 1; m >>= 1)
#pragma unroll
        for (int j = 0; j < 4; ++j) sum[j] += __shfl_xor(sum[j], m);

#pragma unroll
    for (int j = 0; j < 4; ++j) {
        int t = q0w + g * 4 + j;
        float svm = NEGc - mx[j];
        float mnum = __builtin_amdgcn_rcpf(fmaf(0.5f * svm, svm, 1.0f - svm));
        float inv = __builtin_amdgcn_rcpf(sum[j] + (float)(Tc - 1 - t) * mnum + EPSc);
#pragma unroll
        for (int n = 0; n < 4; ++n) {
            o[((size_t)(b * Tc + t)) * Dc + h * 64 + n * 16 + l15] = f2b(oacc[n][j] * inv);
        }
    }
}

extern "C" void kernel_launch(void* const* d_in, const int* in_sizes, int n_in,
                              void* d_out, int out_size, void* d_ws, size_t ws_size,
                              hipStream_t stream) {
    const int* ids = (const int*)d_in[0];
    const float* embed_w = (const float*)d_in[1];
    const float* qkv_w = (const float*)d_in[2];
    const float* out_w = (const float*)d_in[3];
    const float* gate_w = (const float*)d_in[4];
    const float* wout_w = (const float*)d_in[5];
    const float* n1 = (const float*)d_in[6];
    const float* n2 = (const float*)d_in[7];
    const float* nf = (const float*)d_in[8];
    float* outp = (float*)d_out;

    char* ws = (char*)d_ws;
    float* x = (float*)(ws + 0);                                   //  8,388,608
    unsigned short* h = (unsigned short*)(ws + 8388608);           //  4,194,304 (h / o share)
    unsigned short* Qh = (unsigned short*)(ws + 12582912);         //  4,194,304
    unsigned short* Kh = (unsigned short*)(ws + 16777216);         //  4,194,304
    unsigned short* Vt = (unsigned short*)(ws + 20971520);         //  4,194,304
    unsigned short* g = (unsigned short*)(ws + 25165824);          // 11,272,192
    unsigned short* w1 = (unsigned short*)(ws + 36438016);         //  6,291,456 (wq)
    unsigned short* wo_b = (unsigned short*)(ws + 42729472);       //  2,097,152
    unsigned short* wg_b = (unsigned short*)(ws + 44826624);       // 11,272,192 (end 56,098,816; gate GEMM
                                                                   //   over-reads 256KB into ww_b, discarded)
    unsigned short* ww_b = (unsigned short*)(ws + 56098816);       //  5,636,096 (end 61,734,912)
    unsigned short* emb_b = (unsigned short*)(ws + 12582912);      // 65,536,000 overlay (end 78,118,912)

    dim3 blk(256);

    k_embed<<<dim3(Mc), blk, 0, stream>>>(ids, embed_w, x);

    for (int l = 0; l < 4; l++) {
        const float* wq = qkv_w + (size_t)l * 3 * Dc * Dc;
        const float* wo = out_w + (size_t)l * Dc * Dc;
        const float* wg = gate_w + (size_t)l * 2 * Fc * Dc;
        const float* ww = wout_w + (size_t)l * Dc * Fc;

        // weight conversions + menorm1 fused in ONE kernel (independent work)
        k_conv_layer<<<dim3(12672), blk, 0, stream>>>(wq, wo, wg, ww, w1, wo_b, wg_b, ww_b,
                                                      x, n1 + (size_t)l * Dc, h);
        // qkv GEMM fused: writes Qh, Kh, Vt directly (N=3072, K=1024)
        k_mfma_gemm<2, 128><<<dim3(16, 24), blk, 0, stream>>>(h, w1, nullptr, nullptr, Qh, Kh, Vt, 3 * Dc, Dc);
        // attention -> o (bf16, into h buffer); KVBLK=128, double-buffered staging
        k_attn_mfma<<<dim3(512), blk, 0, stream>>>(Qh, Kh, Vt, h);
        // x = x + o @ wo^T  (N=1024, K=1024), BM=64 -> 256 wgs
        k_mfma_gemm<1, 64><<<dim3(32, 8), blk, 0, stream>>>(h, wo_b, x, x, nullptr, nullptr, nullptr, Dc, Dc);
        // h = me_norm(x, n2)
        k_menorm_b<<<dim3(Mc), blk, 0, stream>>>(x, n2 + (size_t)l * Dc, h);
        // gate GEMM fused via 256^2 8ph (grid 8x22 covers N=5632; cols >= 5504 discarded)
        k_gemm_8ph<1><<<dim3(8, 22), dim3(512), 0, stream>>>(h, wg_b, nullptr, g, Gp, Dc);
        // x = x + g @ ww^T  (N=1024, K=2752 padded), BM=64 -> 256 wgs
        k_mfma_gemm<1, 64><<<dim3(32, 8), blk, 0, stream>>>(g, ww_b, x, x, nullptr, nullptr, nullptr, Dc, Fp);
    }

    // final: embedding convert + final menorm fused (independent work)
    k_conv_final<<<dim3(34048), blk, 0, stream>>>(embed_w, emb_b, x, nf, h);
    // logits = h @ embed^T  (N=32000, K=1024) — r20 pipelined 256^2, identity XCD map
    k_gemm_8ph<0><<<dim3(8, 125), dim3(512), 0, stream>>>(h, emb_b, outp, nullptr, 32000, Dc);
}

// Round 24
// 879.679 us; speedup vs baseline: 1.0673x; 1.0427x over previous
//
#include <hip/hip_runtime.h>
#include <math.h>

typedef __attribute__((ext_vector_type(8))) short bf16x8;
typedef __attribute__((ext_vector_type(4))) float f32x4;

namespace {
constexpr int Bc = 2, Tc = 1024, Dc = 1024, Hc = 16, Fc = 2730;
constexpr int Fp = 2752;   // padded F (K of wout GEMM)
constexpr int Gp = 5504;   // padded 2F (N of gate GEMM)
constexpr int Mc = Bc * Tc;               // 2048 rows
constexpr float EPSc = 1e-6f;
constexpr float NEGc = -10000.0f;
constexpr float SCALEc = 0.125f;          // 1/sqrt(64)
}

// fp32 -> bf16 RTNE (finite values only, which holds here)
__device__ __forceinline__ unsigned short f2b(float f) {
    unsigned int u = __float_as_uint(f);
    u += 0x7FFFu + ((u >> 16) & 1u);
    return (unsigned short)(u >> 16);
}

// ---------------- embedding gather (fp32 x) ----------------
__global__ void k_embed(const int* __restrict__ ids, const float* __restrict__ ew,
                        float* __restrict__ x) {
    int row = blockIdx.x;
    int id = ids[row];
    const float4* src = (const float4*)(ew + (size_t)id * Dc);
    float4* dst = (float4*)(x + (size_t)row * Dc);
    dst[threadIdx.x] = src[threadIdx.x];
}

// ---------------- me_norm body (shared by fused kernels) ----------------
__device__ __forceinline__ void menorm_row(const float* __restrict__ x, const float* __restrict__ w,
                                           unsigned short* __restrict__ out, int row) {
    float4 v = ((const float4*)(x + (size_t)row * Dc))[threadIdx.x];
    float s = fabsf(v.x) + fabsf(v.y) + fabsf(v.z) + fabsf(v.w);
#pragma unroll
    for (int m = 32; m >= 1; m >>= 1) s += __shfl_xor(s, m);
    __shared__ float ws4[4];
    if ((threadIdx.x & 63) == 0) ws4[threadIdx.x >> 6] = s;
    __syncthreads();
    float tot = ws4[0] + ws4[1] + ws4[2] + ws4[3];
    float inv = 1.0f / (tot / (float)Dc + EPSc);
    float4 wv = ((const float4*)w)[threadIdx.x];
    ushort4 o;
    o.x = f2b(v.x * inv * wv.x);
    o.y = f2b(v.y * inv * wv.y);
    o.z = f2b(v.z * inv * wv.z);
    o.w = f2b(v.w * inv * wv.w);
    ((ushort4*)(out + (size_t)row * Dc))[threadIdx.x] = o;
}

// ---------------- me_norm standalone (n2 path) ----------------
__global__ void k_menorm_b(const float* __restrict__ x, const float* __restrict__ w,
                           unsigned short* __restrict__ out) {
    menorm_row(x, w, out, blockIdx.x);
}

// ---------------- fused per-layer: weight convert (wq|wo|wg-ilv|ww-padk) + menorm1 ----------------
__global__ void k_conv_layer(const float* __restrict__ wq, const float* __restrict__ wo,
                             const float* __restrict__ wg, const float* __restrict__ ww,
                             unsigned short* __restrict__ wq_b, unsigned short* __restrict__ wo_b,
                             unsigned short* __restrict__ wg_b, unsigned short* __restrict__ ww_b,
                             const float* __restrict__ x, const float* __restrict__ n1,
                             unsigned short* __restrict__ h) {
    int r = blockIdx.x;
    int c4 = threadIdx.x * 4;
    if (r < 3072) {
        float4 v = *(const float4*)(wq + (size_t)r * Dc + c4);
        ushort4 o; o.x = f2b(v.x); o.y = f2b(v.y); o.z = f2b(v.z); o.w = f2b(v.w);
        *(ushort4*)(wq_b + (size_t)r * Dc + c4) = o;
    } else if (r < 4096) {
        int rr = r - 3072;
        float4 v = *(const float4*)(wo + (size_t)rr * Dc + c4);
        ushort4 o; o.x = f2b(v.x); o.y = f2b(v.y); o.z = f2b(v.z); o.w = f2b(v.w);
        *(ushort4*)(wo_b + (size_t)rr * Dc + c4) = o;
    } else if (r < 9600) {
        int rr = r - 4096;                // 0..Gp-1
        ushort4 o;
        if (rr < 2 * Fc) {
            int src = (rr >> 1) + (rr & 1) * Fc;
            float4 v = *(const float4*)(wg + (size_t)src * Dc + c4);
            o.x = f2b(v.x); o.y = f2b(v.y); o.z = f2b(v.z); o.w = f2b(v.w);
        } else {
            o.x = o.y = o.z = o.w = 0;
        }
        *(ushort4*)(wg_b + (size_t)rr * Dc + c4) = o;
    } else if (r < 10624) {
        int rr = r - 9600;                // 0..1023
        for (int c = threadIdx.x; c < Fp; c += 256) {
            float v = (c < Fc) ? ww[(size_t)rr * Fc + c] : 0.0f;
            ww_b[(size_t)rr * Fp + c] = f2b(v);
        }
    } else {
        menorm_row(x, n1, h, r - 10624);  // 0..2047
    }
}

// ---------------- fused final: embedding convert + final menorm ----------------
__global__ void k_conv_final(const float* __restrict__ ew, unsigned short* __restrict__ emb_b,
                             const float* __restrict__ x, const float* __restrict__ nf,
                             unsigned short* __restrict__ h) {
    int r = blockIdx.x;
    if (r < 32000) {
        size_t i = (size_t)r * Dc + threadIdx.x * 4;
        float4 v = *(const float4*)(ew + i);
        ushort4 o;
        o.x = f2b(v.x); o.y = f2b(v.y); o.z = f2b(v.z); o.w = f2b(v.w);
        *(ushort4*)(emb_b + i) = o;
    } else {
        menorm_row(x, nf, h, r - 32000);
    }
}

// ---------------- MFMA GEMM, r11-pipelined 2-barrier tile (BM = 128), MODE 2 qkv fusion ----------------
template <int MODE, int BM>
__global__ __launch_bounds__(256) void k_mfma_gemm(
    const unsigned short* __restrict__ A, const unsigned short* __restrict__ Bw,
    const float* __restrict__ Res, float* __restrict__ C,
    unsigned short* __restrict__ U0, unsigned short* __restrict__ U1,
    unsigned short* __restrict__ U2, int N, int K) {
    constexpr int MFR = BM / 32;          // A-frags / acc rows per wave (2 or 4)
    __shared__ __align__(16) unsigned short As[2][BM * 64];
    __shared__ __align__(16) unsigned short Bs[2][128 * 64];
    const int tid = threadIdx.x;
    const int lane = tid & 63;
    const int wid = tid >> 6;
    const int wr = wid >> 1, wc = wid & 1;
    const int l15 = lane & 15, g = lane >> 4;

    const int nwg = gridDim.x * gridDim.y;
    int w = blockIdx.y * gridDim.x + blockIdx.x;
    int f = (nwg & 7) ? w : ((w & 7) * (nwg >> 3) + (w >> 3));
    const int bm = (f % gridDim.x) * BM, bn = (f / gridDim.x) * 128;

    f32x4 acc[MFR][4] = {};
    const int nk = K >> 6;

#define STAGEL(buf, kt)                                                                          \
    {                                                                                            \
        _Pragma("unroll") for (int it = 0; it < MFR; ++it) {                                     \
            int ci = it * 256 + tid;                                                             \
            int r = ci >> 3, sc = (ci & 7) ^ (r & 7);                                            \
            __builtin_amdgcn_global_load_lds(                                                    \
                (const __attribute__((address_space(1))) void*)(A + (size_t)(bm + r) * K + (kt) * 64 + sc * 8), \
                (__attribute__((address_space(3))) void*)(&As[buf][ci * 8]), 16, 0, 0);          \
        }                                                                                        \
        _Pragma("unroll") for (int it = 0; it < 4; ++it) {                                       \
            int ci = it * 256 + tid;                                                             \
            int r = ci >> 3, sc = (ci & 7) ^ (r & 7);                                            \
            __builtin_amdgcn_global_load_lds(                                                    \
                (const __attribute__((address_space(1))) void*)(Bw + (size_t)(bn + r) * K + (kt) * 64 + sc * 8), \
                (__attribute__((address_space(3))) void*)(&Bs[buf][ci * 8]), 16, 0, 0);          \
        }                                                                                        \
    }

    STAGEL(0, 0);
    STAGEL(1, 1);
    if constexpr (BM == 128) { asm volatile("s_waitcnt vmcnt(8)" ::: "memory"); }
    else                     { asm volatile("s_waitcnt vmcnt(6)" ::: "memory"); }
    __builtin_amdgcn_s_barrier();

    for (int kt = 0; kt < nk; ++kt) {
        const int buf = kt & 1;
        const unsigned short* Ab = As[buf];
        const unsigned short* Bb = Bs[buf];
        bf16x8 bfr[4][2];
#pragma unroll
        for (int n = 0; n < 4; ++n) {
            int col = wc * 64 + n * 16 + l15;
#pragma unroll
            for (int kk = 0; kk < 2; ++kk) {
                int kc = kk * 4 + g;
                bfr[n][kk] = *(const bf16x8*)&Bb[(col * 8 + (kc ^ (col & 7))) * 8];
            }
        }
        bf16x8 af[MFR][2];
#pragma unroll
        for (int m = 0; m < MFR; ++m) {
            int row = wr * (BM / 2) + m * 16 + l15;
#pragma unroll
            for (int kk = 0; kk < 2; ++kk) {
                int kc = kk * 4 + g;
                af[m][kk] = *(const bf16x8*)&Ab[(row * 8 + (kc ^ (row & 7))) * 8];
            }
        }
        __builtin_amdgcn_s_setprio(1);
#pragma unroll
        for (int m = 0; m < MFR - 1; ++m)
#pragma unroll
            for (int kk = 0; kk < 2; ++kk)
#pragma unroll
                for (int n = 0; n < 4; ++n)
                    acc[m][n] = __builtin_amdgcn_mfma_f32_16x16x32_bf16(af[m][kk], bfr[n][kk], acc[m][n], 0, 0, 0);
        __builtin_amdgcn_s_setprio(0);
        asm volatile("s_waitcnt lgkmcnt(0)" ::: "memory");
        __builtin_amdgcn_s_barrier();
        if (kt + 2 < nk) STAGEL(buf, kt + 2);
        __builtin_amdgcn_s_setprio(1);
#pragma unroll
        for (int kk = 0; kk < 2; ++kk)
#pragma unroll
            for (int n = 0; n < 4; ++n)
                acc[MFR - 1][n] = __builtin_amdgcn_mfma_f32_16x16x32_bf16(af[MFR - 1][kk], bfr[n][kk], acc[MFR - 1][n], 0, 0, 0);
        __builtin_amdgcn_s_setprio(0);
        if (kt + 2 < nk) {
            if constexpr (BM == 128) { asm volatile("s_waitcnt vmcnt(8)" ::: "memory"); }
            else                     { asm volatile("s_waitcnt vmcnt(6)" ::: "memory"); }
        } else {
            asm volatile("s_waitcnt vmcnt(0)" ::: "memory");
        }
        __builtin_amdgcn_s_barrier();
    }
#undef STAGEL

    // epilogue: C/D mapping col = lane&15, row = (lane>>4)*4 + j  [m89-verified]
#pragma unroll
    for (int m = 0; m < MFR; ++m) {
        int row0 = bm + wr * (BM / 2) + m * 16 + (g << 2);
#pragma unroll
        for (int n = 0; n < 4; ++n) {
            int col = bn + wc * 64 + n * 16 + l15;
            if constexpr (MODE == 0 || MODE == 1) {
#pragma unroll
                for (int j = 0; j < 4; ++j) {
                    size_t idx = (size_t)(row0 + j) * N + col;
                    float v = acc[m][n][j];
                    if (MODE == 1) v += Res[idx];
                    C[idx] = v;
                }
            } else if constexpr (MODE == 2) {
                if (col < 2048) {
                    unsigned short* dst = (col < 1024) ? U0 : U1;
                    int hh = (col & 1023) >> 6, dh = col & 63;
#pragma unroll
                    for (int j = 0; j < 4; ++j) {
                        int row = row0 + j;
                        int b = row >> 10, t = row & 1023;
                        dst[((size_t)((b * Hc + hh) * Tc + t)) * 64 + dh] = f2b(acc[m][n][j]);
                    }
                } else {
                    int hh = (col >> 6) & 15, dh = col & 63;
                    int b = row0 >> 10, t = row0 & 1023;
                    ushort4 o4;
                    o4.x = f2b(acc[m][n][0]); o4.y = f2b(acc[m][n][1]);
                    o4.z = f2b(acc[m][n][2]); o4.w = f2b(acc[m][n][3]);
                    *(ushort4*)&U2[((size_t)((b * Hc + hh) * 64 + dh)) * Tc + t] = o4;
                }
            }
        }
    }
}

// ---------------- 64x64 residual GEMM: C = Res + A@B^T (2-barrier pipeline) ----------------
// Grid (M/64, N/64) = (32,16) -> 512 blocks = 2 blocks/CU (was 256 = 1/CU at BM64xBN128).
// IDENTITY map: x-fastest round-robin -> XCD k owns bm = {k, k+8, k+16, k+24} (512KB A-slice
// L2-resident; B streams via L3). 4 waves x (16 rows x 64 cols); LDS 32KB dbuf; stage = 4
// issues/tile -> counted vmcnt(4); MFMA split 4+4 around the restage. Same chunk-XOR involution.
__global__ __launch_bounds__(256) void k_gemm_res(
    const unsigned short* __restrict__ A, const unsigned short* __restrict__ Bw,
    const float* __restrict__ Res, float* __restrict__ C, int N, int K) {
    __shared__ __align__(16) unsigned short As[2][64 * 64];
    __shared__ __align__(16) unsigned short Bs[2][64 * 64];
    const int tid = threadIdx.x;
    const int lane = tid & 63, wid = tid >> 6;
    const int l15 = lane & 15, g = lane >> 4;

    const int bm = blockIdx.x * 64;
    const int bn = blockIdx.y * 64;

    f32x4 acc[4] = {};
    const int nk = K >> 6;

#define STAGER(buf, kt)                                                                          \
    {                                                                                            \
        _Pragma("unroll") for (int it = 0; it < 2; ++it) {                                       \
            int ci = it * 256 + tid;                                                             \
            int r = ci >> 3, sc = (ci & 7) ^ (r & 7);                                            \
            __builtin_amdgcn_global_load_lds(                                                    \
                (const __attribute__((address_space(1))) void*)(A + (size_t)(bm + r) * K + (kt) * 64 + sc * 8), \
                (__attribute__((address_space(3))) void*)(&As[buf][ci * 8]), 16, 0, 0);          \
        }                                                                                        \
        _Pragma("unroll") for (int it = 0; it < 2; ++it) {                                       \
            int ci = it * 256 + tid;                                                             \
            int r = ci >> 3, sc = (ci & 7) ^ (r & 7);                                            \
            __builtin_amdgcn_global_load_lds(                                                    \
                (const __attribute__((address_space(1))) void*)(Bw + (size_t)(bn + r) * K + (kt) * 64 + sc * 8), \
                (__attribute__((address_space(3))) void*)(&Bs[buf][ci * 8]), 16, 0, 0);          \
        }                                                                                        \
    }

    STAGER(0, 0);
    STAGER(1, 1);
    asm volatile("s_waitcnt vmcnt(4)" ::: "memory");   // tile 0 landed (tile 1 in flight)
    __builtin_amdgcn_s_barrier();

    for (int kt = 0; kt < nk; ++kt) {
        const int buf = kt & 1;
        const unsigned short* Ab = As[buf];
        const unsigned short* Bb = Bs[buf];
        bf16x8 bfr[4][2];
#pragma unroll
        for (int n = 0; n < 4; ++n) {
            int col = n * 16 + l15;
#pragma unroll
            for (int kk = 0; kk < 2; ++kk) {
                int kc = kk * 4 + g;
                bfr[n][kk] = *(const bf16x8*)&Bb[(col * 8 + (kc ^ (col & 7))) * 8];
            }
        }
        bf16x8 af[2];
        {
            int row = wid * 16 + l15;
#pragma unroll
            for (int kk = 0; kk < 2; ++kk) {
                int kc = kk * 4 + g;
                af[kk] = *(const bf16x8*)&Ab[(row * 8 + (kc ^ (row & 7))) * 8];
            }
        }
        // kk = 0 (overlaps ds_reads above)
        __builtin_amdgcn_s_setprio(1);
#pragma unroll
        for (int n = 0; n < 4; ++n)
            acc[n] = __builtin_amdgcn_mfma_f32_16x16x32_bf16(af[0], bfr[n][0], acc[n], 0, 0, 0);
        __builtin_amdgcn_s_setprio(0);
        asm volatile("s_waitcnt lgkmcnt(0)" ::: "memory");
        __builtin_amdgcn_s_barrier();
        if (kt + 2 < nk) STAGER(buf, kt + 2);
        // kk = 1 (overlaps restage issue)
        __builtin_amdgcn_s_setprio(1);
#pragma unroll
        for (int n = 0; n < 4; ++n)
            acc[n] = __builtin_amdgcn_mfma_f32_16x16x32_bf16(af[1], bfr[n][1], acc[n], 0, 0, 0);
        __builtin_amdgcn_s_setprio(0);
        if (kt + 2 < nk) {
            asm volatile("s_waitcnt vmcnt(4)" ::: "memory");   // tile kt+1 landed
        } else {
            asm volatile("s_waitcnt vmcnt(0)" ::: "memory");   // tail drain
        }
        __builtin_amdgcn_s_barrier();
    }
#undef STAGER

    // epilogue: C = Res + acc; C/D mapping col = lane&15, row = (lane>>4)*4 + j
    int row0 = bm + wid * 16 + (g << 2);
#pragma unroll
    for (int n = 0; n < 4; ++n) {
        int col = bn + n * 16 + l15;
#pragma unroll
        for (int j = 0; j < 4; ++j) {
            size_t idx = (size_t)(row0 + j) * N + col;
            C[idx] = Res[idx] + acc[n][j];
        }
    }
}

// ---------------- 256x256 GEMM, pipelined 2-barrier tile (r20 exact, ~170us on logits) ----------------
// IDENTITY XCD map. GM 0: C = A@B^T fp32. GM 1: gate-fused epilogue -> G bf16 [2048][Fp].
template <int GM>
__global__ __launch_bounds__(512, 2) void k_gemm_8ph(
    const unsigned short* __restrict__ A, const unsigned short* __restrict__ Bw,
    float* __restrict__ C, unsigned short* __restrict__ G, int N, int K) {
    __shared__ __align__(16) unsigned short As[2][256 * 64];
    __shared__ __align__(16) unsigned short Bs[2][256 * 64];
    const int tid = threadIdx.x;
    const int lane = tid & 63, wid = tid >> 6;
    const int wm = wid >> 2, wn = wid & 3;
    const int l15 = lane & 15, g = lane >> 4;

    const int bm = blockIdx.x * 256;
    const int bn = blockIdx.y * 256;

    const int nk = K >> 6;
    f32x4 acc[8][4] = {};

#define STAGE8(buf, kt)                                                                          \
    {                                                                                            \
        _Pragma("unroll") for (int it = 0; it < 4; ++it) {                                       \
            int ci = it * 512 + tid;                                                             \
            int r = ci >> 3, c = (ci & 7) ^ (r & 7);                                             \
            __builtin_amdgcn_global_load_lds(                                                    \
                (const __attribute__((address_space(1))) void*)(A + (size_t)(bm + r) * K + (kt) * 64 + c * 8), \
                (__attribute__((address_space(3))) void*)(&As[buf][ci * 8]), 16, 0, 0);          \
        }                                                                                        \
        _Pragma("unroll") for (int it = 0; it < 4; ++it) {                                       \
            int ci = it * 512 + tid;                                                             \
            int r = ci >> 3, c = (ci & 7) ^ (r & 7);                                             \
            __builtin_amdgcn_global_load_lds(                                                    \
                (const __attribute__((address_space(1))) void*)(Bw + (size_t)(bn + r) * K + (kt) * 64 + c * 8), \
                (__attribute__((address_space(3))) void*)(&Bs[buf][ci * 8]), 16, 0, 0);          \
        }                                                                                        \
    }

    STAGE8(0, 0);
    STAGE8(1, 1);
    asm volatile("s_waitcnt vmcnt(8)" ::: "memory");
    __builtin_amdgcn_s_barrier();

    for (int kt = 0; kt < nk; ++kt) {
        const int buf = kt & 1;
        const unsigned short* Ab = As[buf];
        const unsigned short* Bb = Bs[buf];
        bf16x8 bfr[4][2];
#pragma unroll
        for (int n = 0; n < 4; ++n) {
            int col = wn * 64 + n * 16 + l15;
#pragma unroll
            for (int kk = 0; kk < 2; ++kk) {
                int kc = kk * 4 + g;
                bfr[n][kk] = *(const bf16x8*)&Bb[(col * 8 + (kc ^ (col & 7))) * 8];
            }
        }
        bf16x8 af[4][2][2];
#pragma unroll
        for (int p = 0; p < 4; ++p)
#pragma unroll
            for (int le = 0; le < 2; ++le) {
                int row = wm * 128 + (p * 2 + le) * 16 + l15;
#pragma unroll
                for (int kk = 0; kk < 2; ++kk) {
                    int kc = kk * 4 + g;
                    af[p][le][kk] = *(const bf16x8*)&Ab[(row * 8 + (kc ^ (row & 7))) * 8];
                }
            }
        __builtin_amdgcn_s_setprio(1);
#pragma unroll
        for (int p = 0; p < 3; ++p)
#pragma unroll
            for (int kk = 0; kk < 2; ++kk)
#pragma unroll
                for (int le = 0; le < 2; ++le)
#pragma unroll
                    for (int n = 0; n < 4; ++n)
                        acc[p * 2 + le][n] = __builtin_amdgcn_mfma_f32_16x16x32_bf16(
                            af[p][le][kk], bfr[n][kk], acc[p * 2 + le][n], 0, 0, 0);
        __builtin_amdgcn_s_setprio(0);
        asm volatile("s_waitcnt lgkmcnt(0)" ::: "memory");
        __builtin_amdgcn_s_barrier();
        if (kt + 2 < nk) STAGE8(buf, kt + 2);
        __builtin_amdgcn_s_setprio(1);
#pragma unroll
        for (int kk = 0; kk < 2; ++kk)
#pragma unroll
            for (int le = 0; le < 2; ++le)
#pragma unroll
                for (int n = 0; n < 4; ++n)
                    acc[6 + le][n] = __builtin_amdgcn_mfma_f32_16x16x32_bf16(
                        af[3][le][kk], bfr[n][kk], acc[6 + le][n], 0, 0, 0);
        __builtin_amdgcn_s_setprio(0);
        if (kt + 2 < nk) {
            asm volatile("s_waitcnt vmcnt(8)" ::: "memory");
        } else {
            asm volatile("s_waitcnt vmcnt(0)" ::: "memory");
        }
        __builtin_amdgcn_s_barrier();
    }
#undef STAGE8

    // epilogue: C/D mapping col = lane&15, row = (lane>>4)*4 + j
#pragma unroll
    for (int m = 0; m < 8; ++m) {
        int row0 = bm + wm * 128 + m * 16 + (g << 2);
#pragma unroll
        for (int n = 0; n < 4; ++n) {
            int col = bn + wn * 64 + n * 16 + l15;
            if constexpr (GM == 0) {
#pragma unroll
                for (int j = 0; j < 4; ++j)
                    C[(size_t)(row0 + j) * N + col] = acc[m][n][j];
            } else {  // gate fusion: cols pair (2f, 2f+1) = (gate, val)
                float pv[4];
#pragma unroll
                for (int j = 0; j < 4; ++j) pv[j] = __shfl_xor(acc[m][n][j], 1);
                if ((l15 & 1) == 0) {
                    int fq = col >> 1;
                    if (fq < Fp) {
#pragma unroll
                        for (int j = 0; j < 4; ++j) {
                            float gate = acc[m][n][j], val = pv[j];
                            float sigma = 0.5f * (gate / (fabsf(gate) + 1.0f) + 1.0f);
                            G[(size_t)(row0 + j) * Fp + fq] = f2b(gate * sigma * val);
                        }
                    }
                }
            }
        }
    }
}

// ---------------- MFMA attention, KVBLK=128 + double-buffered staging (r22, proven) ----------------
__global__ __launch_bounds__(256) void k_attn_mfma(
    const unsigned short* __restrict__ Qh, const unsigned short* __restrict__ Kh,
    const unsigned short* __restrict__ Vt, unsigned short* __restrict__ o) {
    const int d0 = blockIdx.x;
    const int r0 = d0 & 255;
    const int slot = d0 >> 8;
    const int bh = r0 >> 3;
    const int e = r0 & 7;
    const int bx = slot ? (15 - e) : e;
    const int q0 = bx * 64;
    const int b = bh >> 4, h = bh & 15;
    const float slope = exp2f(-0.5f * (float)(h + 1));

    __shared__ __align__(16) unsigned short Ks[2][128 * 64];
    __shared__ __align__(16) unsigned short Vs[2][64 * 128];
    __shared__ __align__(16) unsigned short Ps[4][16 * 128];

    const int tid = threadIdx.x, lane = tid & 63, wid = tid >> 6;
    const int q0w = q0 + wid * 16;
    const int l15 = lane & 15, g = lane >> 4;

    const unsigned short* qbase = Qh + ((size_t)(bh * Tc + q0w + l15)) * 64 + g * 8;
    bf16x8 qf[2];
    qf[0] = *(const bf16x8*)qbase;
    qf[1] = *(const bf16x8*)(qbase + 32);

    const int nt = (bx >> 1) + 1;

#define STAGE_K128(kb, it)                                                                       \
    {                                                                                            \
        _Pragma("unroll") for (int i = 0; i < 4; ++i) {                                          \
            int ci = i * 256 + tid;                                                              \
            int r = ci >> 3, sc = (ci & 7) ^ (r & 7);                                            \
            __builtin_amdgcn_global_load_lds(                                                    \
                (const __attribute__((address_space(1))) void*)(Kh + ((size_t)(bh * Tc + (it) * 128 + r)) * 64 + sc * 8), \
                (__attribute__((address_space(3))) void*)(&Ks[kb][ci * 8]), 16, 0, 0);           \
        }                                                                                        \
    }
#define STAGE_V128(kb, it)                                                                       \
    {                                                                                            \
        _Pragma("unroll") for (int i = 0; i < 4; ++i) {                                          \
            int ci = i * 256 + tid;                                                              \
            int dh = ci >> 4, th = (ci >> 3) & 1, c = ci & 7;                                    \
            int sc = c ^ (dh & 7);                                                               \
            __builtin_amdgcn_global_load_lds(                                                    \
                (const __attribute__((address_space(1))) void*)(Vt + ((size_t)(bh * 64 + dh)) * Tc + (it) * 128 + th * 64 + sc * 8), \
                (__attribute__((address_space(3))) void*)(&Vs[kb][ci * 8]), 16, 0, 0);           \
        }                                                                                        \
    }

    // ---------- pass A: exact row max (double-buffered K staging) ----------
    f32x4 mx = {-3e38f, -3e38f, -3e38f, -3e38f};
    STAGE_K128(0, 0);
    for (int it = 0; it < nt; ++it) {
        const int kb = it & 1;
        if (it + 1 < nt) {
            STAGE_K128(kb ^ 1, it + 1);
            asm volatile("s_waitcnt vmcnt(4)" ::: "memory");
        } else {
            asm volatile("s_waitcnt vmcnt(0)" ::: "memory");
        }
        __builtin_amdgcn_s_barrier();
        const int st = it * 128;
#pragma unroll
        for (int si = 0; si < 8; ++si) {
            f32x4 d = {0.f, 0.f, 0.f, 0.f};
            int r2 = si * 16 + l15;
#pragma unroll
            for (int kc = 0; kc < 2; ++kc) {
                int c2 = kc * 4 + g;
                bf16x8 bk = *(const bf16x8*)&Ks[kb][(r2 * 8 + (c2 ^ (r2 & 7))) * 8];
                d = __builtin_amdgcn_mfma_f32_16x16x32_bf16(qf[kc], bk, d, 0, 0, 0);
            }
            int s = st + r2;
#pragma unroll
            for (int j = 0; j < 4; ++j) {
                int t = q0w + g * 4 + j;
                float scv = (s <= t) ? d[j] * SCALEc - slope * (float)(t - s) : -3e38f;
                mx[j] = fmaxf(mx[j], scv);
            }
        }
        __syncthreads();
    }
#pragma unroll
    for (int m = 8; m >= 1; m >>= 1)
#pragma unroll
        for (int j = 0; j < 4; ++j) mx[j] = fmaxf(mx[j], __shfl_xor(mx[j], m));

    // ---------- pass B: numerators, sum, PV (double-buffered K+V staging) ----------
    f32x4 sum = {0.f, 0.f, 0.f, 0.f};
    f32x4 oacc[4] = {};
    STAGE_K128(0, 0);
    STAGE_V128(0, 0);
    for (int it = 0; it < nt; ++it) {
        const int kb = it & 1;
        if (it + 1 < nt) {
            STAGE_K128(kb ^ 1, it + 1);
            STAGE_V128(kb ^ 1, it + 1);
            asm volatile("s_waitcnt vmcnt(8)" ::: "memory");
        } else {
            asm volatile("s_waitcnt vmcnt(0)" ::: "memory");
        }
        __builtin_amdgcn_s_barrier();
        const int st = it * 128;
#pragma unroll
        for (int si = 0; si < 8; ++si) {
            f32x4 d = {0.f, 0.f, 0.f, 0.f};
            int sl = si * 16 + l15;
#pragma unroll
            for (int kc = 0; kc < 2; ++kc) {
                int c2 = kc * 4 + g;
                bf16x8 bk = *(const bf16x8*)&Ks[kb][(sl * 8 + (c2 ^ (sl & 7))) * 8];
                d = __builtin_amdgcn_mfma_f32_16x16x32_bf16(qf[kc], bk, d, 0, 0, 0);
            }
            int s = st + sl;
            int chunk = sl >> 3, coff = sl & 7;
#pragma unroll
            for (int j = 0; j < 4; ++j) {
                int t = q0w + g * 4 + j;
                int q = g * 4 + j;
                unsigned short pb = 0;
                if (s <= t) {
                    float sv = d[j] * SCALEc - slope * (float)(t - s) - mx[j];
                    float num = __builtin_amdgcn_rcpf(fmaf(0.5f * sv, sv, 1.0f - sv));
                    sum[j] += num;
                    pb = f2b(num);
                }
                Ps[wid][q * 128 + ((chunk & 8) | ((chunk & 7) ^ (q & 7))) * 8 + coff] = pb;
            }
        }
        __syncthreads();
#pragma unroll
        for (int kc2 = 0; kc2 < 4; ++kc2) {
            int c2 = kc2 * 4 + g;
            bf16x8 pa = *(const bf16x8*)&Ps[wid][(l15 * 16 + ((c2 & 8) | ((c2 & 7) ^ (l15 & 7)))) * 8];
#pragma unroll
            for (int n = 0; n < 4; ++n) {
                int r2 = n * 16 + l15;
                bf16x8 vb = *(const bf16x8*)&Vs[kb][(r2 * 16 + ((c2 & 8) | ((c2 & 7) ^ (r2 & 7)))) * 8];
                oacc[n] = __builtin_amdgcn_mfma_f32_16x16x32_bf16(pa, vb, oacc[n], 0, 0, 0);
            }
        }
        __syncthreads();
    }
#undef STAGE_K128
#undef STAGE_V128
#pragma unroll
    for (int m = 8; m >= 1; m >>= 1)
#pragma unroll
        for (int j = 0; j < 4; ++j) sum[j] += __shfl_xor(sum[j], m);

#pragma unroll
    for (int j = 0; j < 4; ++j) {
        int t = q0w + g * 4 + j;
        float svm = NEGc - mx[j];
        float mnum = __builtin_amdgcn_rcpf(fmaf(0.5f * svm, svm, 1.0f - svm));
        float inv = __builtin_amdgcn_rcpf(sum[j] + (float)(Tc - 1 - t) * mnum + EPSc);
#pragma unroll
        for (int n = 0; n < 4; ++n) {
            o[((size_t)(b * Tc + t)) * Dc + h * 64 + n * 16 + l15] = f2b(oacc[n][j] * inv);
        }
    }
}

extern "C" void kernel_launch(void* const* d_in, const int* in_sizes, int n_in,
                              void* d_out, int out_size, void* d_ws, size_t ws_size,
                              hipStream_t stream) {
    const int* ids = (const int*)d_in[0];
    const float* embed_w = (const float*)d_in[1];
    const float* qkv_w = (const float*)d_in[2];
    const float* out_w = (const float*)d_in[3];
    const float* gate_w = (const float*)d_in[4];
    const float* wout_w = (const float*)d_in[5];
    const float* n1 = (const float*)d_in[6];
    const float* n2 = (const float*)d_in[7];
    const float* nf = (const float*)d_in[8];
    float* outp = (float*)d_out;

    char* ws = (char*)d_ws;
    float* x = (float*)(ws + 0);                                   //  8,388,608
    unsigned short* h = (unsigned short*)(ws + 8388608);           //  4,194,304 (h / o share)
    unsigned short* Qh = (unsigned short*)(ws + 12582912);         //  4,194,304
    unsigned short* Kh = (unsigned short*)(ws + 16777216);         //  4,194,304
    unsigned short* Vt = (unsigned short*)(ws + 20971520);         //  4,194,304
    unsigned short* g = (unsigned short*)(ws + 25165824);          // 11,272,192
    unsigned short* w1 = (unsigned short*)(ws + 36438016);         //  6,291,456 (wq)
    unsigned short* wo_b = (unsigned short*)(ws + 42729472);       //  2,097,152
    unsigned short* wg_b = (unsigned short*)(ws + 44826624);       // 11,272,192 (end 56,098,816; gate GEMM
                                                                   //   over-reads 256KB into ww_b, discarded)
    unsigned short* ww_b = (unsigned short*)(ws + 56098816);       //  5,636,096 (end 61,734,912)
    unsigned short* emb_b = (unsigned short*)(ws + 12582912);      // 65,536,000 overlay (end 78,118,912)

    dim3 blk(256);

    k_embed<<<dim3(Mc), blk, 0, stream>>>(ids, embed_w, x);

    for (int l = 0; l < 4; l++) {
        const float* wq = qkv_w + (size_t)l * 3 * Dc * Dc;
        const float* wo = out_w + (size_t)l * Dc * Dc;
        const float* wg = gate_w + (size_t)l * 2 * Fc * Dc;
        const float* ww = wout_w + (size_t)l * Dc * Fc;

        // weight conversions + menorm1 fused in ONE kernel (independent work)
        k_conv_layer<<<dim3(12672), blk, 0, stream>>>(wq, wo, wg, ww, w1, wo_b, wg_b, ww_b,
                                                      x, n1 + (size_t)l * Dc, h);
        // qkv GEMM fused: writes Qh, Kh, Vt directly (N=3072, K=1024)
        k_mfma_gemm<2, 128><<<dim3(16, 24), blk, 0, stream>>>(h, w1, nullptr, nullptr, Qh, Kh, Vt, 3 * Dc, Dc);
        // attention -> o (bf16, into h buffer); KVBLK=128, double-buffered staging
        k_attn_mfma<<<dim3(512), blk, 0, stream>>>(Qh, Kh, Vt, h);
        // x = x + o @ wo^T  (N=1024, K=1024), 64x64 tiles -> 512 wgs = 2 blocks/CU
        k_gemm_res<<<dim3(32, 16), blk, 0, stream>>>(h, wo_b, x, x, Dc, Dc);
        // h = me_norm(x, n2)
        k_menorm_b<<<dim3(Mc), blk, 0, stream>>>(x, n2 + (size_t)l * Dc, h);
        // gate GEMM fused via 256^2 8ph (grid 8x22 covers N=5632; cols >= 5504 discarded)
        k_gemm_8ph<1><<<dim3(8, 22), dim3(512), 0, stream>>>(h, wg_b, nullptr, g, Gp, Dc);
        // x = x + g @ ww^T  (N=1024, K=2752 padded), 64x64 tiles -> 512 wgs
        k_gemm_res<<<dim3(32, 16), blk, 0, stream>>>(g, ww_b, x, x, Dc, Fp);
    }

    // final: embedding convert + final menorm fused (independent work)
    k_conv_final<<<dim3(34048), blk, 0, stream>>>(embed_w, emb_b, x, nf, h);
    // logits = h @ embed^T  (N=32000, K=1024) — r20 pipelined 256^2, identity XCD map
    k_gemm_8ph<0><<<dim3(8, 125), dim3(512), 0, stream>>>(h, emb_b, outp, nullptr, 32000, Dc);
}